// Round 5
// baseline (793.876 us; speedup 1.0000x reference)
//
#include <hip/hip_runtime.h>
#include <hip/hip_bf16.h>
#include <hip/hip_fp8.h>
#include <cstdint>
#include <cstddef>

#define INVS 0.99999500003749968f  // 1/sqrt(1+1e-5)
#define G_GRAPHS 256

using bf16 = __hip_bfloat16;
using short8 = __attribute__((ext_vector_type(8))) short;
using floatx4 = __attribute__((ext_vector_type(4))) float;

// ---------- helpers ----------
__device__ __forceinline__ unsigned short f2bf(float v) {
    union { float f; unsigned u; } x; x.f = v;
    unsigned r = x.u + 0x7fffu + ((x.u >> 16) & 1u);
    return (unsigned short)(r >> 16);
}
__device__ __forceinline__ float bfu(unsigned short u) { return __uint_as_float((unsigned)u << 16); }
__device__ __forceinline__ float fp82f(unsigned char b) {
    __hip_fp8_e4m3 q; q.__x = b; return (float)q;
}
// pack 2 f32 -> 2 bf16 in one u32 (lo = a, hi = b), HW RNE (matches f2bf for finite values)
__device__ __forceinline__ unsigned pk_bf16(float a, float b) {
    unsigned r;
    asm("v_cvt_pk_bf16_f32 %0, %1, %2" : "=v"(r) : "v"(a), "v"(b));
    return r;
}
// pack 4 f32 -> 4 fp8 bytes [a,b,c,d]
__device__ __forceinline__ unsigned pk_fp8x4(float a, float b, float c, float d) {
#if __has_builtin(__builtin_amdgcn_cvt_pk_fp8_f32)
    int u = __builtin_amdgcn_cvt_pk_fp8_f32(a, b, 0, false);
    u = __builtin_amdgcn_cvt_pk_fp8_f32(c, d, u, true);
    return (unsigned)u;
#else
    __hip_fp8_e4m3 qa(a), qb(b), qc(c), qd(d);
    return (unsigned)qa.__x | ((unsigned)qb.__x << 8) | ((unsigned)qc.__x << 16) | ((unsigned)qd.__x << 24);
#endif
}

// ---------- CSR build ----------
__global__ void degi_k(const int* __restrict__ dst, int* __restrict__ degi, int E) {
    int gid = blockIdx.x * 256 + threadIdx.x;
    if (gid < E) atomicAdd(&degi[dst[gid]], 1);
}

__global__ __launch_bounds__(1024) void scan_blk_k(const int* __restrict__ degi,
                                                   int* __restrict__ off,
                                                   int* __restrict__ bsum, int N) {
    __shared__ int buf[1024];
    int t = threadIdx.x;
    int base = blockIdx.x * 2048;
    int i0 = base + 2 * t, i1 = base + 2 * t + 1;
    int v0 = (i0 < N) ? (degi[i0] + 1) : 0;
    int v1 = (i1 < N) ? (degi[i1] + 1) : 0;
    int s = v0 + v1;
    buf[t] = s;
    __syncthreads();
    for (int ofs = 1; ofs < 1024; ofs <<= 1) {
        int add = (t >= ofs) ? buf[t - ofs] : 0;
        __syncthreads();
        buf[t] += add;
        __syncthreads();
    }
    int excl = buf[t] - s;
    if (i0 < N) off[i0] = excl;
    if (i1 < N) off[i1] = excl + v0;
    if (t == 1023) bsum[blockIdx.x] = buf[1023];
}

__global__ void scan_top_k(const int* __restrict__ bsum, int* __restrict__ boff,
                           int* __restrict__ off, int NBLK, int N) {
    if (threadIdx.x == 0 && blockIdx.x == 0) {
        int run = 0;
        for (int i = 0; i < NBLK; ++i) { boff[i] = run; run += bsum[i]; }
        off[N] = run;
    }
}

__global__ void scan_add_k(int* __restrict__ off, const int* __restrict__ boff, int N) {
    int gid = blockIdx.x * 256 + threadIdx.x;
    if (gid < N) off[gid] += boff[gid >> 11];
}

__global__ void fill_csr_k(const int* __restrict__ src, const int* __restrict__ dst,
                           const int* __restrict__ off, int* __restrict__ fillc,
                           int* __restrict__ csr_src, int* __restrict__ csr_dst,
                           int* __restrict__ csr_eid, int E, int N) {
    int gid = blockIdx.x * 256 + threadIdx.x;
    if (gid < E) {
        int d = dst[gid];
        int slot = off[d] + atomicAdd(&fillc[d], 1);
        csr_src[slot] = src[gid];
        csr_dst[slot] = d;
        csr_eid[slot] = gid;
    }
    if (gid < N) {
        int slot = off[gid + 1] - 1;   // reserved last slot = self-loop
        csr_src[slot] = gid;
        csr_dst[slot] = gid;
        csr_eid[slot] = E + gid;       // >= E marks self-loop
    }
}

// ---------- weight prep for MFMA edge MLP1 (factored) ----------
__global__ void conv_weights1_k(const float* __restrict__ w1, const float* __restrict__ w2,
                                short* __restrict__ w1p, short* __restrict__ w1c,
                                short* __restrict__ w2s) {
    int gid = blockIdx.x * 256 + threadIdx.x;
    if (gid < 1024) {
        int f = gid >> 6, lane = gid & 63;
        int kk = f >> 3, tt = f & 7;
        int n = tt * 16 + (lane & 15);
        int k0 = kk * 32 + (lane >> 4) * 8;
        short8 v;
        for (int j = 0; j < 8; ++j) {
            int k = k0 + j;
            float x = (n < 64) ? w1[k * 64 + n] : w1[(64 + k) * 64 + (n - 64)];
            v[j] = (short)f2bf(x);
        }
        *(short8*)(w1p + (long long)gid * 8) = v;
    } else if (gid < 1280) {
        int g2 = gid - 1024;
        int tt = g2 >> 6, lane = g2 & 63;
        int n = tt * 16 + (lane & 15);
        int k0 = (lane >> 4) * 8;
        short8 v;
        for (int j = 0; j < 8; ++j) {
            int k = k0 + j;
            v[j] = (k < 16) ? (short)f2bf(w1[(128 + k) * 64 + n]) : (short)0;
        }
        *(short8*)(w1c + (long long)g2 * 8) = v;
    } else if (gid < 2304) {
        int g2 = gid - 1280;
        int f = g2 >> 6, lane = g2 & 63;
        int kk = f >> 3, tt = f & 7;
        int n = tt * 16 + (lane & 15);
        int k0 = kk * 32 + (lane >> 4) * 8;
        short8 v;
        for (int j = 0; j < 8; ++j) v[j] = (short)f2bf(w2[(k0 + j) * 128 + n]);
        *(short8*)(w2s + (long long)g2 * 8) = v;
    }
}

// ---------- ew prep: ew[128][256] -> frags 4 kk x 16 tt ----------
__global__ void conv_ew_k(const float* __restrict__ ew, short* __restrict__ ews) {
    int gid = blockIdx.x * 256 + threadIdx.x;
    if (gid >= 4096) return;
    int f = gid >> 6, lane = gid & 63;
    int kk = f >> 4, tt = f & 15;
    int n = tt * 16 + (lane & 15);
    int k0 = kk * 32 + (lane >> 4) * 8;
    short8 v;
    for (int j = 0; j < 8; ++j) v[j] = (short)f2bf(ew[(k0 + j) * 256 + n]);
    *(short8*)(ews + (long long)gid * 8) = v;
}

// ---------- node-linear weight prep: [wl|wr] (K x 512) -> frags ----------
template <int K>
__global__ void conv_nodew_k(const float* __restrict__ wl, const float* __restrict__ wr,
                             short* __restrict__ out) {
    int gid = blockIdx.x * 256 + threadIdx.x;
    if (gid >= (K / 32) * 32 * 64) return;
    int f = gid >> 6, lane = gid & 63;
    int kk = f >> 5, tt = f & 31;
    int n = tt * 16 + (lane & 15);
    int k0 = kk * 32 + (lane >> 4) * 8;
    short8 v;
    for (int j = 0; j < 8; ++j) {
        int k = k0 + j;
        float x = (n < 256) ? wl[k * 256 + n] : wr[k * 256 + (n - 256)];
        v[j] = (short)f2bf(x);
    }
    *(short8*)(out + (long long)gid * 8) = v;
}

// ---------- pre2 weight prep ----------
__global__ void conv_pre2w_k(const float* __restrict__ w1, short* __restrict__ out) {
    int gid = blockIdx.x * 256 + threadIdx.x;
    if (gid >= 8 * 16 * 64) return;
    int f = gid >> 6, lane = gid & 63;
    int kk = f >> 4, tt = f & 15;
    int n = tt * 16 + (lane & 15);
    int k0 = kk * 32 + (lane >> 4) * 8;
    short8 v;
    for (int j = 0; j < 8; ++j) {
        int k = k0 + j;
        float x = (n < 128) ? w1[k * 128 + n] : w1[(256 + k) * 128 + (n - 128)];
        v[j] = (short)f2bf(x);
    }
    *(short8*)(out + (long long)gid * 8) = v;
}

// ---------- pre1: pre1[n] = [ x@W1a | x@W1b + b1 ]  (N x 128 bf16) ----------
__global__ __launch_bounds__(256) void pre1_mfma_k(
    const float* __restrict__ x, const short* __restrict__ w1p,
    const float* __restrict__ b1, bf16* __restrict__ pre1, int N) {
    __shared__ short At[16][72];
    __shared__ short Ot[16][136];
    int t = threadIdx.x;
    long long n0 = (long long)blockIdx.x * 16;
    {
        int r = t >> 4, c = t & 15;
        long long n = n0 + r;
        float4 v = {0.f, 0.f, 0.f, 0.f};
        if (n < N) v = *(const float4*)(x + n * 64 + c * 4);
        ushort4 pk;
        pk.x = f2bf(v.x); pk.y = f2bf(v.y); pk.z = f2bf(v.z); pk.w = f2bf(v.w);
        *(ushort4*)&At[r][c * 4] = pk;
    }
    __syncthreads();
    int w = t >> 6, lane = t & 63;
    int nq = w * 2;
    int lr = lane & 15, lq = lane >> 4;
    floatx4 acc[2];
    for (int i = 0; i < 2; ++i) acc[i] = (floatx4){0.f, 0.f, 0.f, 0.f};
    for (int kk = 0; kk < 2; ++kk) {
        short8 a = *(const short8*)&At[lr][kk * 32 + lq * 8];
        for (int tt = 0; tt < 2; ++tt) {
            short8 b = *(const short8*)(w1p + ((long long)((kk * 8 + nq + tt) * 64 + lane)) * 8);
            acc[tt] = __builtin_amdgcn_mfma_f32_16x16x32_bf16(a, b, acc[tt], 0, 0, 0);
        }
    }
    for (int tt = 0; tt < 2; ++tt) {
        int col = (nq + tt) * 16 + lr;
        float bv = (col >= 64) ? b1[col - 64] : 0.f;
        for (int r = 0; r < 4; ++r)
            Ot[lq * 4 + r][col] = (short)f2bf(acc[tt][r] + bv);
    }
    __syncthreads();
    {
        int r = t >> 4, c = t & 15;
        long long n = n0 + r;
        if (n < N)
            *(short8*)(void*)(pre1 + n * 128 + c * 8) = *(const short8*)&Ot[r][c * 8];
    }
}

// ---------- Edge MLP 1 via MFMA (swapped operands, register acc-init, no staging LDS) ----------
// acc = pre1_s[src]+pre1_d[dst](+b1) ; + ea@W1c ; relu ; @W2 ; @ews -> fp8 ee8.
// Per-lane gathers go straight into the MFMA accumulator (bit-identical to LDS staging).
__global__ __launch_bounds__(256) void edge_mlp1_mfma_k(
    const bf16* __restrict__ pre1, const float* __restrict__ ea,
    const int* __restrict__ csr_src, const int* __restrict__ csr_dst,
    const int* __restrict__ csr_eid,
    const short* __restrict__ w1c,
    const short* __restrict__ w2s, const float* __restrict__ b2,
    const short* __restrict__ ews,
    unsigned char* __restrict__ ee8, int NT, int E) {
    __shared__ short Ht[32][72];         // hidden (64 chans)
    __shared__ short A2[32][136];        // ea2 tile (128 chans)
    __shared__ unsigned EtU[32][68];     // fp8 tile (256 chans), 272 B rows
    __shared__ int sdv[32][3];
    int t = threadIdx.x;
    long long s0 = (long long)blockIdx.x * 32;
    if (t < 96) {
        int r = t & 31, which = t >> 5;
        long long s = s0 + r;
        int v = (which == 2) ? E : 0;
        if (s < NT) v = (which == 0) ? csr_src[s] : (which == 1 ? csr_dst[s] : csr_eid[s]);
        sdv[r][which] = v;
    }
    __syncthreads();

    int w = t >> 6, lane = t & 63;
    int sl = (w & 1) * 16 + (lane & 15);   // this lane's slot
    int lq = lane >> 4;
    int srcn = sdv[sl][0], dstn = sdv[sl][1], eid = sdv[sl][2];

    // ea B-fragment for this (slot, k-chunk): k = lq*8+j, valid k<16; self-loops -> 0
    short8 eafr = (short8){0, 0, 0, 0, 0, 0, 0, 0};
    if (lq < 2 && eid < E) {
        float4 v0 = *(const float4*)(ea + (long long)eid * 16 + lq * 8);
        float4 v1 = *(const float4*)(ea + (long long)eid * 16 + lq * 8 + 4);
        union { uint4 u; short8 s; } cv;
        cv.u.x = pk_bf16(v0.x, v0.y); cv.u.y = pk_bf16(v0.z, v0.w);
        cv.u.z = pk_bf16(v1.x, v1.y); cv.u.w = pk_bf16(v1.z, v1.w);
        eafr = cv.s;
    }

    // phase 1: h1 = relu(pre_s+pre_d + ea@W1c)  (64 chans; 2 m-tiles per wave)
    {
        int mb = (w >> 1) * 2;
        floatx4 acc[2];
        #pragma unroll
        for (int tt = 0; tt < 2; ++tt) {
            int ch0 = (mb + tt) * 16 + lq * 4;
            ushort4 vs = *(const ushort4*)(const void*)(pre1 + (long long)srcn * 128 + ch0);
            ushort4 vd = *(const ushort4*)(const void*)(pre1 + (long long)dstn * 128 + 64 + ch0);
            acc[tt] = (floatx4){bfu(vs.x) + bfu(vd.x), bfu(vs.y) + bfu(vd.y),
                                bfu(vs.z) + bfu(vd.z), bfu(vs.w) + bfu(vd.w)};
        }
        #pragma unroll
        for (int tt = 0; tt < 2; ++tt) {
            short8 a = *(const short8*)(w1c + ((long long)((mb + tt) * 64 + lane)) * 8);
            acc[tt] = __builtin_amdgcn_mfma_f32_16x16x32_bf16(a, eafr, acc[tt], 0, 0, 0);
        }
        #pragma unroll
        for (int tt = 0; tt < 2; ++tt) {
            int ch0 = (mb + tt) * 16 + lq * 4;
            uint2 o;
            o.x = pk_bf16(fmaxf(acc[tt][0], 0.f), fmaxf(acc[tt][1], 0.f));
            o.y = pk_bf16(fmaxf(acc[tt][2], 0.f), fmaxf(acc[tt][3], 0.f));
            *(uint2*)&Ht[sl][ch0] = o;
        }
    }
    __syncthreads();

    // phase 2: ea2 = h1 @ W2 + b2  (128 chans; 4 m-tiles per wave)
    {
        int mb = (w >> 1) * 4;
        floatx4 acc2[4];
        #pragma unroll
        for (int i = 0; i < 4; ++i) acc2[i] = (floatx4){0.f, 0.f, 0.f, 0.f};
        #pragma unroll
        for (int kk = 0; kk < 2; ++kk) {
            short8 bfr = *(const short8*)&Ht[sl][kk * 32 + lq * 8];
            #pragma unroll
            for (int tt = 0; tt < 4; ++tt) {
                short8 a = *(const short8*)(w2s + ((long long)((kk * 8 + mb + tt) * 64 + lane)) * 8);
                acc2[tt] = __builtin_amdgcn_mfma_f32_16x16x32_bf16(a, bfr, acc2[tt], 0, 0, 0);
            }
        }
        #pragma unroll
        for (int tt = 0; tt < 4; ++tt) {
            int ch0 = (mb + tt) * 16 + lq * 4;
            float4 bv = *(const float4*)(b2 + ch0);
            uint2 o;
            o.x = pk_bf16(acc2[tt][0] + bv.x, acc2[tt][1] + bv.y);
            o.y = pk_bf16(acc2[tt][2] + bv.z, acc2[tt][3] + bv.w);
            *(uint2*)&A2[sl][ch0] = o;
        }
    }
    __syncthreads();

    // phase 3: ee = ea2 @ ews (K=128 -> 256 chans; 8 m-tiles per wave), fp8 pack into EtU
    {
        int mb = (w >> 1) * 8;
        floatx4 acc3[8];
        #pragma unroll
        for (int i = 0; i < 8; ++i) acc3[i] = (floatx4){0.f, 0.f, 0.f, 0.f};
        #pragma unroll
        for (int kk = 0; kk < 4; ++kk) {
            short8 bfr = *(const short8*)&A2[sl][kk * 32 + lq * 8];
            #pragma unroll
            for (int tt = 0; tt < 8; ++tt) {
                short8 a = *(const short8*)(ews + ((long long)((kk * 16 + mb + tt) * 64 + lane)) * 8);
                acc3[tt] = __builtin_amdgcn_mfma_f32_16x16x32_bf16(a, bfr, acc3[tt], 0, 0, 0);
            }
        }
        #pragma unroll
        for (int tt = 0; tt < 8; ++tt) {
            EtU[sl][(mb + tt) * 4 + lq] = pk_fp8x4(acc3[tt][0], acc3[tt][1], acc3[tt][2], acc3[tt][3]);
        }
    }
    __syncthreads();
    for (int i = t; i < 512; i += 256) {
        int r = i >> 4, c = i & 15;
        long long s = s0 + r;
        if (s < NT)
            *(uint4*)(ee8 + s * 256 + c * 16) = *(const uint4*)&EtU[r][c * 4];
    }
}

// ---------- node linear via MFMA (swapped operands): [N x K] @ [K x 512] + bias ----------
// NOTE: x may alias xr (x1bn overlay) — per-block reads complete before same-row writes.
template <int K, typename T>
__global__ __launch_bounds__(256) void node_linear_mfma_k(
    const T* x, const short* __restrict__ ws,
    const float* __restrict__ bl, const float* __restrict__ br,
    bf16* __restrict__ xl, bf16* xr, int N) {
    __shared__ short At[16][K + 8];
    __shared__ short Ot[16][520];
    int t = threadIdx.x;
    long long n0 = (long long)blockIdx.x * 16;
    if (sizeof(T) == 4) {
        for (int i = t; i < 16 * (K / 4); i += 256) {
            int r = i / (K / 4), c = i % (K / 4);
            long long n = n0 + r;
            float4 v = {0.f, 0.f, 0.f, 0.f};
            if (n < N) v = *(const float4*)((const float*)x + n * K + c * 4);
            ushort4 pk;
            pk.x = f2bf(v.x); pk.y = f2bf(v.y); pk.z = f2bf(v.z); pk.w = f2bf(v.w);
            *(ushort4*)&At[r][c * 4] = pk;
        }
    } else {
        for (int i = t; i < 16 * (K / 8); i += 256) {
            int r = i / (K / 8), c = i % (K / 8);
            long long n = n0 + r;
            short8 v = {0, 0, 0, 0, 0, 0, 0, 0};
            if (n < N) v = *(const short8*)(const void*)((const bf16*)x + n * K + c * 8);
            *(short8*)&At[r][c * 8] = v;
        }
    }
    __syncthreads();

    int w = t >> 6, lane = t & 63;
    int nr = lane & 15, lq = lane >> 4;

    floatx4 acc[8];
    #pragma unroll
    for (int i = 0; i < 8; ++i) acc[i] = (floatx4){0.f, 0.f, 0.f, 0.f};
    for (int kk = 0; kk < K / 32; ++kk) {
        short8 bfr = *(const short8*)&At[nr][kk * 32 + lq * 8];
        #pragma unroll
        for (int tt = 0; tt < 8; ++tt) {
            short8 a = *(const short8*)(ws + ((long long)((kk * 32 + w * 8 + tt) * 64 + lane)) * 8);
            acc[tt] = __builtin_amdgcn_mfma_f32_16x16x32_bf16(a, bfr, acc[tt], 0, 0, 0);
        }
    }
    #pragma unroll
    for (int tt = 0; tt < 8; ++tt) {
        int ch0 = (w * 8 + tt) * 16 + lq * 4;
        const float* bp = (ch0 < 256) ? (bl + ch0) : (br + (ch0 - 256));
        float4 bv = *(const float4*)bp;
        uint2 o;
        o.x = pk_bf16(acc[tt][0] + bv.x, acc[tt][1] + bv.y);
        o.y = pk_bf16(acc[tt][2] + bv.z, acc[tt][3] + bv.w);
        *(uint2*)&Ot[nr][ch0] = o;
    }
    __syncthreads();
    for (int i = t; i < 1024; i += 256) {
        int r = i >> 6, c = i & 63;
        long long n = n0 + r;
        if (n < N) {
            short8 v = *(const short8*)&Ot[r][c * 8];
            if (c < 32) *(short8*)(void*)(xl + n * 256 + c * 8) = v;
            else        *(short8*)(void*)(xr + n * 256 + (c - 32) * 8) = v;
        }
    }
}

// ---------- pre2 (swapped operands): xp = x1bn @ M[256x256] + b1x -> xl ----------
__global__ __launch_bounds__(256) void pre_mfma_k(
    const bf16* __restrict__ x, const short* __restrict__ ws,
    const float* __restrict__ bx, bf16* __restrict__ out, int N) {
    __shared__ short At[16][264];
    __shared__ short Ot[16][264];
    int t = threadIdx.x;
    long long n0 = (long long)blockIdx.x * 16;
    for (int i = t; i < 512; i += 256) {
        int r = i >> 5, c = i & 31;
        long long n = n0 + r;
        short8 v = {0, 0, 0, 0, 0, 0, 0, 0};
        if (n < N) v = *(const short8*)(const void*)(x + n * 256 + c * 8);
        *(short8*)&At[r][c * 8] = v;
    }
    __syncthreads();

    int w = t >> 6, lane = t & 63;
    int nr = lane & 15, lq = lane >> 4;

    floatx4 acc[4];
    #pragma unroll
    for (int i = 0; i < 4; ++i) acc[i] = (floatx4){0.f, 0.f, 0.f, 0.f};
    for (int kk = 0; kk < 8; ++kk) {
        short8 bfr = *(const short8*)&At[nr][kk * 32 + lq * 8];
        #pragma unroll
        for (int tt = 0; tt < 4; ++tt) {
            short8 a = *(const short8*)(ws + ((long long)((kk * 16 + w * 4 + tt) * 64 + lane)) * 8);
            acc[tt] = __builtin_amdgcn_mfma_f32_16x16x32_bf16(a, bfr, acc[tt], 0, 0, 0);
        }
    }
    #pragma unroll
    for (int tt = 0; tt < 4; ++tt) {
        int ch0 = (w * 4 + tt) * 16 + lq * 4;
        float4 bv = *(const float4*)(bx + ch0);
        uint2 o;
        o.x = pk_bf16(acc[tt][0] + bv.x, acc[tt][1] + bv.y);
        o.y = pk_bf16(acc[tt][2] + bv.z, acc[tt][3] + bv.w);
        *(uint2*)&Ot[nr][ch0] = o;
    }
    __syncthreads();
    for (int i = t; i < 512; i += 256) {
        int r = i >> 5, c = i & 31;
        long long n = n0 + r;
        if (n < N)
            *(short8*)(void*)(out + n * 256 + c * 8) = *(const short8*)&Ot[r][c * 8];
    }
}

// ---------- Fused GATv2 attention + aggregation + finalize ----------
template <bool L1>
__global__ __launch_bounds__(256) void gat_fused_k(
    const unsigned char* __restrict__ ee8, const bf16* __restrict__ xl, const bf16* xr,
    const int* __restrict__ off, const int* __restrict__ csr_src,
    const float* __restrict__ att, const float* __restrict__ bias,
    const float* __restrict__ bng, const float* __restrict__ bnb,
    const int* __restrict__ batch,
    bf16* x1bn, float* __restrict__ pooled, int N) {
    __shared__ float ps[4][260];
    __shared__ int bid[4];
    int t = threadIdx.x;
    int w = t >> 6, lane = t & 63;
    int n = blockIdx.x * 4 + w;
    bool valid = n < N;
    int c0 = lane * 4;
    float o0 = 0.f, o1 = 0.f, o2 = 0.f, o3 = 0.f;
    if (valid) {
        ushort4 xrp = *(const ushort4*)(const void*)(xr + (long long)n * 256 + c0);
        ushort4 xop = *(const ushort4*)(const void*)(xl + (long long)n * 256 + c0);
        float xr0 = bfu(xrp.x), xr1 = bfu(xrp.y), xr2 = bfu(xrp.z), xr3 = bfu(xrp.w);
        float4 atv = *(const float4*)(att + c0);
        float a0 = 0.f, a1 = 0.f, a2 = 0.f, a3 = 0.f, dacc = 0.f;
        float es0 = 0.f, es1 = 0.f, es2 = 0.f, es3 = 0.f;
        int beg = off[n], end1 = off[n + 1] - 1;
        ushort4 xlp;
        unsigned ep;
        {
            int sid = csr_src[beg];
            xlp = *(const ushort4*)(const void*)(xl + (long long)sid * 256 + c0);
            ep = *(const unsigned*)(ee8 + (long long)beg * 256 + c0);
        }
        for (int i = beg; i < end1; ++i) {
            ushort4 cx = xlp;
            unsigned ce = ep;
            if (i + 1 < end1) {
                int sid = csr_src[i + 1];
                xlp = *(const ushort4*)(const void*)(xl + (long long)sid * 256 + c0);
                ep = *(const unsigned*)(ee8 + (long long)(i + 1) * 256 + c0);
            }
            float x0 = bfu(cx.x), x1 = bfu(cx.y), x2 = bfu(cx.z), x3 = bfu(cx.w);
            float e0 = fp82f(ce & 0xff);
            float e1 = fp82f((ce >> 8) & 0xff);
            float e2 = fp82f((ce >> 16) & 0xff);
            float e3 = fp82f(ce >> 24);
            es0 += e0; es1 += e1; es2 += e2; es3 += e3;
            float m0 = x0 + xr0 + e0;
            float m1 = x1 + xr1 + e1;
            float m2 = x2 + xr2 + e2;
            float m3 = x3 + xr3 + e3;
            m0 = m0 > 0.f ? m0 : 0.2f * m0;
            m1 = m1 > 0.f ? m1 : 0.2f * m1;
            m2 = m2 > 0.f ? m2 : 0.2f * m2;
            m3 = m3 > 0.f ? m3 : 0.2f * m3;
            float p = atv.x * m0 + atv.y * m1 + atv.z * m2 + atv.w * m3;
            p += __shfl_xor(p, 1, 64);
            p += __shfl_xor(p, 2, 64);
            p += __shfl_xor(p, 4, 64);
            p += __shfl_xor(p, 8, 64);
            float ex = expf(p);
            a0 += ex * x0; a1 += ex * x1; a2 += ex * x2; a3 += ex * x3;
            dacc += ex;
        }
        // self-loop term: edge feature = mean of incoming ee
        {
            float rdv = 1.f / fmaxf((float)(end1 - beg), 1.f);
            float x0 = bfu(xop.x), x1 = bfu(xop.y), x2 = bfu(xop.z), x3 = bfu(xop.w);
            float m0 = x0 + xr0 + es0 * rdv;
            float m1 = x1 + xr1 + es1 * rdv;
            float m2 = x2 + xr2 + es2 * rdv;
            float m3 = x3 + xr3 + es3 * rdv;
            m0 = m0 > 0.f ? m0 : 0.2f * m0;
            m1 = m1 > 0.f ? m1 : 0.2f * m1;
            m2 = m2 > 0.f ? m2 : 0.2f * m2;
            m3 = m3 > 0.f ? m3 : 0.2f * m3;
            float p = atv.x * m0 + atv.y * m1 + atv.z * m2 + atv.w * m3;
            p += __shfl_xor(p, 1, 64);
            p += __shfl_xor(p, 2, 64);
            p += __shfl_xor(p, 4, 64);
            p += __shfl_xor(p, 8, 64);
            float ex = expf(p);
            a0 += ex * x0; a1 += ex * x1; a2 += ex * x2; a3 += ex * x3;
            dacc += ex;
        }
        float inv = 1.f / dacc;
        o0 = fmaxf(a0 * inv + bias[c0],     0.f);
        o1 = fmaxf(a1 * inv + bias[c0 + 1], 0.f);
        o2 = fmaxf(a2 * inv + bias[c0 + 2], 0.f);
        o3 = fmaxf(a3 * inv + bias[c0 + 3], 0.f);
        if (L1) {
            ushort4 o;
            o.x = f2bf(bng[c0]     * (o0 * INVS) + bnb[c0]);
            o.y = f2bf(bng[c0 + 1] * (o1 * INVS) + bnb[c0 + 1]);
            o.z = f2bf(bng[c0 + 2] * (o2 * INVS) + bnb[c0 + 2]);
            o.w = f2bf(bng[c0 + 3] * (o3 * INVS) + bnb[c0 + 3]);
            *(ushort4*)(void*)(x1bn + (long long)n * 256 + c0) = o;
        }
    }
    if (lane == 0) bid[w] = valid ? batch[n] : -1;
    ps[w][c0]     = o0;
    ps[w][c0 + 1] = o1;
    ps[w][c0 + 2] = o2;
    ps[w][c0 + 3] = o3;
    __syncthreads();
    int b0 = bid[0];
    bool same = (b0 >= 0)
             && (bid[1] < 0 || bid[1] == b0)
             && (bid[2] < 0 || bid[2] == b0)
             && (bid[3] < 0 || bid[3] == b0);
    if (same) {
        float s = ps[0][t] + ps[1][t] + ps[2][t] + ps[3][t];
        atomicAdd(&pooled[(long long)b0 * 256 + t], s);
    } else if (valid) {
        long long pb = (long long)bid[w] * 256 + c0;
        atomicAdd(&pooled[pb],     o0);
        atomicAdd(&pooled[pb + 1], o1);
        atomicAdd(&pooled[pb + 2], o2);
        atomicAdd(&pooled[pb + 3], o3);
    }
}

// ---------- global MLP layer1 ----------
__global__ void global_mlp1_k(const float* __restrict__ pooled,
                              const float* __restrict__ w1, const float* __restrict__ b1,
                              const float* __restrict__ w2, const float* __restrict__ b2,
                              const float* __restrict__ bng, const float* __restrict__ bnb,
                              float* __restrict__ u1bn) {
    __shared__ float pr[256];
    __shared__ float h[256];
    int t = threadIdx.x, g = blockIdx.x;
    pr[t] = pooled[g * 256 + t];
    __syncthreads();
    float acc = b1[t];
    for (int k = 0; k < 256; ++k) acc += pr[k] * w1[(256 + k) * 256 + t];
    h[t] = fmaxf(acc, 0.f);
    __syncthreads();
    float a2 = b2[t];
    for (int k = 0; k < 256; ++k) a2 += h[k] * w2[k * 256 + t];
    u1bn[g * 256 + t] = bng[t] * (a2 * INVS) + bnb[t];
}

// ---------- weight prep for MFMA edge MLP2 (+ b1x for pre path) ----------
__global__ void conv_weights_k(const float* __restrict__ w1, const float* __restrict__ w2,
                               const float* __restrict__ b1,
                               const float* __restrict__ bg, const float* __restrict__ bb,
                               short* __restrict__ w1s, short* __restrict__ w2s,
                               float* __restrict__ b1x) {
    int gid = blockIdx.x * 256 + threadIdx.x;
    if (gid < 10240) {
        int f = gid >> 6, lane = gid & 63;
        int kk = f >> 3, tt = f & 7;
        int n = tt * 16 + (lane & 15);
        int k0 = kk * 32 + (lane >> 4) * 8;
        short8 v;
        for (int j = 0; j < 8; ++j) {
            int k = k0 + j;
            float x = w1[k * 128 + n];
            if (k >= 512) x *= bg[k - 512] * INVS;
            v[j] = (short)f2bf(x);
        }
        *(short8*)(w1s + (long long)gid * 8) = v;
    } else if (gid < 12288) {
        int g2 = gid - 10240;
        int f = g2 >> 6, lane = g2 & 63;
        int kk = f >> 3, tt = f & 7;
        int n = tt * 16 + (lane & 15);
        int k0 = kk * 32 + (lane >> 4) * 8;
        short8 v;
        for (int j = 0; j < 8; ++j) v[j] = (short)f2bf(w2[(k0 + j) * 128 + n]);
        *(short8*)(w2s + (long long)g2 * 8) = v;
    } else if (gid < 12544) {
        int j = gid - 12288;
        b1x[j] = 0.f;
    } else if (gid < 12672) {
        int j = gid - 12544;
        float acc = b1[j];
        for (int c = 0; c < 128; ++c) acc += bb[c] * w1[(512 + c) * 128 + j];
        b1x[128 + j] = acc;
    }
}

// ---------- Edge MLP 2 via MFMA (swapped operands, register acc-init); ea2 recomputed ----------
__global__ __launch_bounds__(256) void edge_mlp2_mfma_k(
    const bf16* __restrict__ xpre, const bf16* __restrict__ pre1,
    const float* __restrict__ ea,
    const int* __restrict__ csr_src, const int* __restrict__ csr_dst,
    const int* __restrict__ csr_eid,
    const short* __restrict__ w1c, const short* __restrict__ w2s1,
    const float* __restrict__ e1_b2,
    const short* __restrict__ w1s,       // uses kk 16..19 (ea rows, BN-folded)
    const short* __restrict__ w2s, const float* __restrict__ b2,
    const short* __restrict__ ews,
    unsigned char* __restrict__ ee8, int NT, int E) {
    __shared__ short At[32][136];
    __shared__ short Ht[32][136];        // dead after B2 -> Et alias (32 x 272 B)
    __shared__ int sdv[32][3];
    unsigned char* Et = (unsigned char*)&Ht[0][0];
    int t = threadIdx.x;
    long long s0 = (long long)blockIdx.x * 32;
    if (t < 96) {
        int r = t & 31, which = t >> 5;
        long long s = s0 + r;
        int v = (which == 2) ? E : 0;
        if (s < NT) v = (which == 0) ? csr_src[s] : (which == 1 ? csr_dst[s] : csr_eid[s]);
        sdv[r][which] = v;
    }
    __syncthreads();

    int w = t >> 6, lane = t & 63;
    int sl = (w & 1) * 16 + (lane & 15);
    int lq = lane >> 4;
    int srcn = sdv[sl][0], dstn = sdv[sl][1], eid = sdv[sl][2];

    // ea B-fragment (same as edge_mlp1)
    short8 eafr = (short8){0, 0, 0, 0, 0, 0, 0, 0};
    if (lq < 2 && eid < E) {
        float4 v0 = *(const float4*)(ea + (long long)eid * 16 + lq * 8);
        float4 v1 = *(const float4*)(ea + (long long)eid * 16 + lq * 8 + 4);
        union { uint4 u; short8 s; } cv;
        cv.u.x = pk_bf16(v0.x, v0.y); cv.u.y = pk_bf16(v0.z, v0.w);
        cv.u.z = pk_bf16(v1.x, v1.y); cv.u.w = pk_bf16(v1.z, v1.w);
        eafr = cv.s;
    }

    // phase A1: h1 = relu(pre1_s+pre1_d + ea@W1c)  (64 chans)
    {
        int mb = (w >> 1) * 2;
        floatx4 acc[2];
        #pragma unroll
        for (int tt = 0; tt < 2; ++tt) {
            int ch0 = (mb + tt) * 16 + lq * 4;
            ushort4 vs = *(const ushort4*)(const void*)(pre1 + (long long)srcn * 128 + ch0);
            ushort4 vd = *(const ushort4*)(const void*)(pre1 + (long long)dstn * 128 + 64 + ch0);
            acc[tt] = (floatx4){bfu(vs.x) + bfu(vd.x), bfu(vs.y) + bfu(vd.y),
                                bfu(vs.z) + bfu(vd.z), bfu(vs.w) + bfu(vd.w)};
        }
        #pragma unroll
        for (int tt = 0; tt < 2; ++tt) {
            short8 a = *(const short8*)(w1c + ((long long)((mb + tt) * 64 + lane)) * 8);
            acc[tt] = __builtin_amdgcn_mfma_f32_16x16x32_bf16(a, eafr, acc[tt], 0, 0, 0);
        }
        #pragma unroll
        for (int tt = 0; tt < 2; ++tt) {
            int ch0 = (mb + tt) * 16 + lq * 4;
            uint2 o;
            o.x = pk_bf16(fmaxf(acc[tt][0], 0.f), fmaxf(acc[tt][1], 0.f));
            o.y = pk_bf16(fmaxf(acc[tt][2], 0.f), fmaxf(acc[tt][3], 0.f));
            *(uint2*)&Ht[sl][ch0] = o;
        }
    }
    __syncthreads();

    // phase A2: ea2 = h1@W2s1 + e1_b2 -> At  (128 chans)
    {
        int mb = (w >> 1) * 4;
        floatx4 acc2[4];
        #pragma unroll
        for (int i = 0; i < 4; ++i) acc2[i] = (floatx4){0.f, 0.f, 0.f, 0.f};
        #pragma unroll
        for (int kk = 0; kk < 2; ++kk) {
            short8 bfr = *(const short8*)&Ht[sl][kk * 32 + lq * 8];
            #pragma unroll
            for (int tt = 0; tt < 4; ++tt) {
                short8 a = *(const short8*)(w2s1 + ((long long)((kk * 8 + mb + tt) * 64 + lane)) * 8);
                acc2[tt] = __builtin_amdgcn_mfma_f32_16x16x32_bf16(a, bfr, acc2[tt], 0, 0, 0);
            }
        }
        #pragma unroll
        for (int tt = 0; tt < 4; ++tt) {
            int ch0 = (mb + tt) * 16 + lq * 4;
            float4 bv = *(const float4*)(e1_b2 + ch0);
            uint2 o;
            o.x = pk_bf16(acc2[tt][0] + bv.x, acc2[tt][1] + bv.y);
            o.y = pk_bf16(acc2[tt][2] + bv.z, acc2[tt][3] + bv.w);
            *(uint2*)&At[sl][ch0] = o;
        }
    }
    __syncthreads();

    // phase B1: h = relu(pre2_s+pre2_d + ea2@W1s[kk16..19])  (128 chans)
    {
        int mb = (w >> 1) * 4;
        floatx4 acc[4];
        #pragma unroll
        for (int tt = 0; tt < 4; ++tt) {
            int ch0 = (mb + tt) * 16 + lq * 4;
            ushort4 vs = *(const ushort4*)(const void*)(xpre + (long long)srcn * 256 + ch0);
            ushort4 vd = *(const ushort4*)(const void*)(xpre + (long long)dstn * 256 + 128 + ch0);
            acc[tt] = (floatx4){bfu(vs.x) + bfu(vd.x), bfu(vs.y) + bfu(vd.y),
                                bfu(vs.z) + bfu(vd.z), bfu(vs.w) + bfu(vd.w)};
        }
        #pragma unroll
        for (int kk = 0; kk < 4; ++kk) {
            short8 bfr = *(const short8*)&At[sl][kk * 32 + lq * 8];
            #pragma unroll
            for (int tt = 0; tt < 4; ++tt) {
                short8 a = *(const short8*)(w1s + ((long long)(((16 + kk) * 8 + mb + tt) * 64 + lane)) * 8);
                acc[tt] = __builtin_amdgcn_mfma_f32_16x16x32_bf16(a, bfr, acc[tt], 0, 0, 0);
            }
        }
        __syncthreads();   // Ht reads of A1 done (A2 barrier); protect Ht writes vs nothing—At reads above done per-wave; keep order
        #pragma unroll
        for (int tt = 0; tt < 4; ++tt) {
            int ch0 = (mb + tt) * 16 + lq * 4;
            uint2 o;
            o.x = pk_bf16(fmaxf(acc[tt][0], 0.f), fmaxf(acc[tt][1], 0.f));
            o.y = pk_bf16(fmaxf(acc[tt][2], 0.f), fmaxf(acc[tt][3], 0.f));
            *(uint2*)&Ht[sl][ch0] = o;
        }
    }
    __syncthreads();

    // phase B2: ea2' = h @ W2 + b2 -> At  (128 chans)
    {
        int mb = (w >> 1) * 4;
        floatx4 acc2[4];
        #pragma unroll
        for (int i = 0; i < 4; ++i) acc2[i] = (floatx4){0.f, 0.f, 0.f, 0.f};
        #pragma unroll
        for (int kk = 0; kk < 4; ++kk) {
            short8 bfr = *(const short8*)&Ht[sl][kk * 32 + lq * 8];
            #pragma unroll
            for (int tt = 0; tt < 4; ++tt) {
                short8 a = *(const short8*)(w2s + ((long long)((kk * 8 + mb + tt) * 64 + lane)) * 8);
                acc2[tt] = __builtin_amdgcn_mfma_f32_16x16x32_bf16(a, bfr, acc2[tt], 0, 0, 0);
            }
        }
        __syncthreads();   // all Ht reads done before Et (aliasing Ht) is written in B3
        #pragma unroll
        for (int tt = 0; tt < 4; ++tt) {
            int ch0 = (mb + tt) * 16 + lq * 4;
            float4 bv = *(const float4*)(b2 + ch0);
            uint2 o;
            o.x = pk_bf16(acc2[tt][0] + bv.x, acc2[tt][1] + bv.y);
            o.y = pk_bf16(acc2[tt][2] + bv.z, acc2[tt][3] + bv.w);
            *(uint2*)&At[sl][ch0] = o;
        }
    }
    __syncthreads();

    // phase B3: ee = ea2' @ ews (K=128 -> 256 chans), fp8 pack into Et (aliases dead Ht)
    {
        int mb = (w >> 1) * 8;
        floatx4 acc3[8];
        #pragma unroll
        for (int i = 0; i < 8; ++i) acc3[i] = (floatx4){0.f, 0.f, 0.f, 0.f};
        #pragma unroll
        for (int kk = 0; kk < 4; ++kk) {
            short8 bfr = *(const short8*)&At[sl][kk * 32 + lq * 8];
            #pragma unroll
            for (int tt = 0; tt < 8; ++tt) {
                short8 a = *(const short8*)(ews + ((long long)((kk * 16 + mb + tt) * 64 + lane)) * 8);
                acc3[tt] = __builtin_amdgcn_mfma_f32_16x16x32_bf16(a, bfr, acc3[tt], 0, 0, 0);
            }
        }
        #pragma unroll
        for (int tt = 0; tt < 8; ++tt) {
            int ch0 = (mb + tt) * 16 + lq * 4;
            *(unsigned*)(Et + sl * 272 + ch0) = pk_fp8x4(acc3[tt][0], acc3[tt][1], acc3[tt][2], acc3[tt][3]);
        }
    }
    __syncthreads();
    for (int i = t; i < 512; i += 256) {
        int r = i >> 4, c = i & 15;
        long long s = s0 + r;
        if (s < NT && sdv[r][2] < E)
            *(uint4*)(ee8 + s * 256 + c * 16) = *(const uint4*)(Et + r * 272 + c * 16);
    }
}

// ---------- final global MLP + head ----------
__global__ void final_mlp_k(const float* __restrict__ u1bn, const float* __restrict__ pooled,
                            const float* __restrict__ w1, const float* __restrict__ b1,
                            const float* __restrict__ w2, const float* __restrict__ b2,
                            const float* __restrict__ f1w, const float* __restrict__ f1b,
                            const float* __restrict__ f2w, const float* __restrict__ f2b,
                            float* __restrict__ out) {
    __shared__ float ub[256], pb[256], h[256], u2[256];
    int t = threadIdx.x, g = blockIdx.x;
    ub[t] = u1bn[g * 256 + t];
    pb[t] = pooled[g * 256 + t];
    __syncthreads();
    float acc = b1[t];
    for (int k = 0; k < 256; ++k)
        acc += ub[k] * w1[k * 256 + t] + pb[k] * w1[(256 + k) * 256 + t];
    h[t] = fmaxf(acc, 0.f);
    __syncthreads();
    float a2 = b2[t];
    for (int k = 0; k < 256; ++k) a2 += h[k] * w2[k * 256 + t];
    u2[t] = a2;
    __syncthreads();
    float fv = 0.f;
    if (t < 64) {
        float a3 = f1b[t];
        for (int k = 0; k < 256; ++k) a3 += u2[k] * f1w[k * 64 + t];
        fv = fmaxf(a3, 0.f) * f2w[t];
    }
    for (int off = 32; off; off >>= 1) fv += __shfl_down(fv, off, 64);
    if (t == 0) out[g] = fv + f2b[0];
}

// ---------- launch ----------
extern "C" void kernel_launch(void* const* d_in, const int* in_sizes, int n_in,
                              void* d_out, int out_size, void* d_ws, size_t ws_size,
                              hipStream_t stream) {
    const float* x         = (const float*)d_in[0];
    const float* edge_attr = (const float*)d_in[1];
    const float* e1_w1 = (const float*)d_in[2];
    const float* e1_b1 = (const float*)d_in[3];
    const float* e1_w2 = (const float*)d_in[4];
    const float* e1_b2 = (const float*)d_in[5];
    const float* g1_lw = (const float*)d_in[6];
    const float* g1_lb = (const float*)d_in[7];
    const float* g1_rw = (const float*)d_in[8];
    const float* g1_rb = (const float*)d_in[9];
    const float* g1_ew = (const float*)d_in[10];
    const float* g1_att = (const float*)d_in[11];
    const float* g1_bias = (const float*)d_in[12];
    const float* u1_w1 = (const float*)d_in[13];
    const float* u1_b1 = (const float*)d_in[14];
    const float* u1_w2 = (const float*)d_in[15];
    const float* u1_b2 = (const float*)d_in[16];
    const float* bn_n_g = (const float*)d_in[17];
    const float* bn_n_b = (const float*)d_in[18];
    const float* bn_e_g = (const float*)d_in[19];
    const float* bn_e_b = (const float*)d_in[20];
    const float* bn_u_g = (const float*)d_in[21];
    const float* bn_u_b = (const float*)d_in[22];
    const float* e2_w1 = (const float*)d_in[23];
    const float* e2_b1 = (const float*)d_in[24];
    const float* e2_w2 = (const float*)d_in[25];
    const float* e2_b2 = (const float*)d_in[26];
    const float* g2_lw = (const float*)d_in[27];
    const float* g2_lb = (const float*)d_in[28];
    const float* g2_rw = (const float*)d_in[29];
    const float* g2_rb = (const float*)d_in[30];
    const float* g2_ew = (const float*)d_in[31];
    const float* g2_att = (const float*)d_in[32];
    const float* g2_bias = (const float*)d_in[33];
    const float* u2_w1 = (const float*)d_in[34];
    const float* u2_b1 = (const float*)d_in[35];
    const float* u2_w2 = (const float*)d_in[36];
    const float* u2_b2 = (const float*)d_in[37];
    const float* fc1_w = (const float*)d_in[38];
    const float* fc1_b = (const float*)d_in[39];
    const float* fc2_w = (const float*)d_in[40];
    const float* fc2_b = (const float*)d_in[41];
    const int* edge_index = (const int*)d_in[42];
    const int* batch = (const int*)d_in[43];

    const int N = in_sizes[0] / 64;
    const int E = in_sizes[1] / 16;
    const int NT = E + N;
    const int G = G_GRAPHS;
    const int* src = edge_index;
    const int* dst = edge_index + E;
    const int NB = (NT + 31) / 32;
    const int NSB = (N + 2047) / 2048;   // scan blocks

    // workspace carve (x1bn aliases xr; pre2 lives in xl during edge_mlp2)
    char* p = (char*)d_ws;
    auto alloc = [&](size_t bytes) { char* r = p; p += (bytes + 255) & ~(size_t)255; return r; };
    bf16* xl    = (bf16*)alloc((size_t)N * 256 * 2);
    bf16* xr    = (bf16*)alloc((size_t)N * 256 * 2);
    bf16* x1bn  = xr;
    unsigned char* ee8 = (unsigned char*)alloc((size_t)NT * 256);
    bf16* pre1  = (bf16*)alloc((size_t)N * 128 * 2);
    int* degi   = (int*)alloc((size_t)N * 4);
    int* off    = (int*)alloc((size_t)(N + 1) * 4);
    int* fillc  = (int*)alloc((size_t)N * 4);
    int* csr_src = (int*)alloc((size_t)NT * 4);
    int* csr_dst = (int*)alloc((size_t)NT * 4);
    int* csr_eid = (int*)alloc((size_t)NT * 4);
    int* bsum   = (int*)alloc((size_t)(NSB + 1) * 4);
    int* boff   = (int*)alloc((size_t)(NSB + 1) * 4);
    float* pooled = (float*)alloc((size_t)G * 256 * 4);
    float* u1bn = (float*)alloc((size_t)G * 256 * 4);
    short* w1s  = (short*)alloc((size_t)20 * 8 * 64 * 8 * 2);
    short* w2s  = (short*)alloc((size_t)4 * 8 * 64 * 8 * 2);
    float* b1x  = (float*)alloc((size_t)256 * 4);
    short* w1p  = (short*)alloc((size_t)16 * 64 * 8 * 2);
    short* w1c  = (short*)alloc((size_t)4 * 64 * 8 * 2);
    short* w2s1 = (short*)alloc((size_t)16 * 64 * 8 * 2);
    short* ews1 = (short*)alloc((size_t)4 * 16 * 64 * 8 * 2);
    short* ews2 = (short*)alloc((size_t)4 * 16 * 64 * 8 * 2);
    short* nw1  = (short*)alloc((size_t)2 * 32 * 64 * 8 * 2);
    short* nw2  = (short*)alloc((size_t)8 * 32 * 64 * 8 * 2);
    short* nwp  = (short*)alloc((size_t)8 * 16 * 64 * 8 * 2);

    // ===== CSR build =====
    hipMemsetAsync(degi, 0, (size_t)N * 4, stream);
    hipMemsetAsync(fillc, 0, (size_t)N * 4, stream);
    hipMemsetAsync(pooled, 0, (size_t)G * 256 * 4, stream);
    degi_k<<<(E + 255) / 256, 256, 0, stream>>>(dst, degi, E);
    scan_blk_k<<<NSB, 1024, 0, stream>>>(degi, off, bsum, N);
    scan_top_k<<<1, 64, 0, stream>>>(bsum, boff, off, NSB, N);
    scan_add_k<<<(N + 255) / 256, 256, 0, stream>>>(off, boff, N);
    fill_csr_k<<<(max(E, N) + 255) / 256, 256, 0, stream>>>(src, dst, off, fillc,
                                                            csr_src, csr_dst, csr_eid, E, N);

    // ===== layer 1 =====
    conv_weights1_k<<<9, 256, 0, stream>>>(e1_w1, e1_w2, w1p, w1c, w2s1);
    conv_ew_k<<<16, 256, 0, stream>>>(g1_ew, ews1);
    conv_ew_k<<<16, 256, 0, stream>>>(g2_ew, ews2);
    conv_nodew_k<64><<<16, 256, 0, stream>>>(g1_lw, g1_rw, nw1);
    conv_nodew_k<256><<<64, 256, 0, stream>>>(g2_lw, g2_rw, nw2);
    conv_pre2w_k<<<32, 256, 0, stream>>>(e2_w1, nwp);
    pre1_mfma_k<<<(N + 15) / 16, 256, 0, stream>>>(x, w1p, e1_b1, pre1, N);
    edge_mlp1_mfma_k<<<NB, 256, 0, stream>>>(pre1, edge_attr, csr_src, csr_dst, csr_eid,
                                             w1c, w2s1, e1_b2, ews1, ee8, NT, E);
    node_linear_mfma_k<64, float><<<(N + 15) / 16, 256, 0, stream>>>(x, nw1, g1_lb, g1_rb, xl, xr, N);
    gat_fused_k<true><<<(N + 3) / 4, 256, 0, stream>>>(ee8, xl, xr, off, csr_src,
                                                       g1_att, g1_bias, bn_n_g, bn_n_b,
                                                       batch, x1bn, pooled, N);
    global_mlp1_k<<<G, 256, 0, stream>>>(pooled, u1_w1, u1_b1, u1_w2, u1_b2, bn_u_g, bn_u_b, u1bn);

    // ===== layer 2 =====
    conv_weights_k<<<50, 256, 0, stream>>>(e2_w1, e2_w2, e2_b1, bn_e_g, bn_e_b, w1s, w2s, b1x);
    pre_mfma_k<<<(N + 15) / 16, 256, 0, stream>>>(x1bn, nwp, b1x, xl, N);
    edge_mlp2_mfma_k<<<NB, 256, 0, stream>>>(xl, pre1, edge_attr, csr_src, csr_dst, csr_eid,
                                             w1c, w2s1, e1_b2, w1s, w2s, e2_b2, ews2,
                                             ee8, NT, E);
    node_linear_mfma_k<256, bf16><<<(N + 15) / 16, 256, 0, stream>>>(x1bn, nw2, g2_lb, g2_rb, xl, xr, N);
    hipMemsetAsync(pooled, 0, (size_t)G * 256 * 4, stream);
    gat_fused_k<false><<<(N + 3) / 4, 256, 0, stream>>>(ee8, xl, xr, off, csr_src,
                                                        g2_att, g2_bias, nullptr, nullptr,
                                                        batch, nullptr, pooled, N);
    final_mlp_k<<<G, 256, 0, stream>>>(u1bn, pooled, u2_w1, u2_b1, u2_w2, u2_b2,
                                       fc1_w, fc1_b, fc2_w, fc2_b, (float*)d_out);
}

// Round 6
// 704.447 us; speedup vs baseline: 1.1270x; 1.1270x over previous
//
#include <hip/hip_runtime.h>
#include <hip/hip_bf16.h>
#include <hip/hip_fp8.h>
#include <cstdint>
#include <cstddef>

#define INVS 0.99999500003749968f  // 1/sqrt(1+1e-5)
#define G_GRAPHS 256

using bf16 = __hip_bfloat16;
using short8 = __attribute__((ext_vector_type(8))) short;
using floatx4 = __attribute__((ext_vector_type(4))) float;

// ---------- helpers ----------
__device__ __forceinline__ unsigned short f2bf(float v) {
    union { float f; unsigned u; } x; x.f = v;
    unsigned r = x.u + 0x7fffu + ((x.u >> 16) & 1u);
    return (unsigned short)(r >> 16);
}
__device__ __forceinline__ float bfu(unsigned short u) { return __uint_as_float((unsigned)u << 16); }
__device__ __forceinline__ float fp82f(unsigned char b) {
    __hip_fp8_e4m3 q; q.__x = b; return (float)q;
}
// pack 2 f32 -> 2 bf16 in one u32 (lo = a, hi = b), HW RNE (matches f2bf for finite values)
__device__ __forceinline__ unsigned pk_bf16(float a, float b) {
    unsigned r;
    asm("v_cvt_pk_bf16_f32 %0, %1, %2" : "=v"(r) : "v"(a), "v"(b));
    return r;
}
// pack 4 f32 -> 4 fp8 bytes [a,b,c,d]
__device__ __forceinline__ unsigned pk_fp8x4(float a, float b, float c, float d) {
#if __has_builtin(__builtin_amdgcn_cvt_pk_fp8_f32)
    int u = __builtin_amdgcn_cvt_pk_fp8_f32(a, b, 0, false);
    u = __builtin_amdgcn_cvt_pk_fp8_f32(c, d, u, true);
    return (unsigned)u;
#else
    __hip_fp8_e4m3 qa(a), qb(b), qc(c), qd(d);
    return (unsigned)qa.__x | ((unsigned)qb.__x << 8) | ((unsigned)qc.__x << 16) | ((unsigned)qd.__x << 24);
#endif
}

// ---------- CSR build ----------
__global__ void degi_k(const int* __restrict__ dst, int* __restrict__ degi, int E) {
    int gid = blockIdx.x * 256 + threadIdx.x;
    if (gid < E) atomicAdd(&degi[dst[gid]], 1);
}

__global__ __launch_bounds__(1024) void scan_blk_k(const int* __restrict__ degi,
                                                   int* __restrict__ off,
                                                   int* __restrict__ bsum, int N) {
    __shared__ int buf[1024];
    int t = threadIdx.x;
    int base = blockIdx.x * 2048;
    int i0 = base + 2 * t, i1 = base + 2 * t + 1;
    int v0 = (i0 < N) ? (degi[i0] + 1) : 0;
    int v1 = (i1 < N) ? (degi[i1] + 1) : 0;
    int s = v0 + v1;
    buf[t] = s;
    __syncthreads();
    for (int ofs = 1; ofs < 1024; ofs <<= 1) {
        int add = (t >= ofs) ? buf[t - ofs] : 0;
        __syncthreads();
        buf[t] += add;
        __syncthreads();
    }
    int excl = buf[t] - s;
    if (i0 < N) off[i0] = excl;
    if (i1 < N) off[i1] = excl + v0;
    if (t == 1023) bsum[blockIdx.x] = buf[1023];
}

__global__ void scan_top_k(const int* __restrict__ bsum, int* __restrict__ boff,
                           int* __restrict__ off, int NBLK, int N) {
    if (threadIdx.x == 0 && blockIdx.x == 0) {
        int run = 0;
        for (int i = 0; i < NBLK; ++i) { boff[i] = run; run += bsum[i]; }
        off[N] = run;
    }
}

__global__ void scan_add_k(int* __restrict__ off, const int* __restrict__ boff, int N) {
    int gid = blockIdx.x * 256 + threadIdx.x;
    if (gid < N) off[gid] += boff[gid >> 11];
}

__global__ void fill_csr_k(const int* __restrict__ src, const int* __restrict__ dst,
                           const int* __restrict__ off, int* __restrict__ fillc,
                           int* __restrict__ csr_src, int* __restrict__ csr_dst,
                           int* __restrict__ csr_eid, int E, int N) {
    int gid = blockIdx.x * 256 + threadIdx.x;
    if (gid < E) {
        int d = dst[gid];
        int slot = off[d] + atomicAdd(&fillc[d], 1);
        csr_src[slot] = src[gid];
        csr_dst[slot] = d;
        csr_eid[slot] = gid;
    }
    if (gid < N) {
        int slot = off[gid + 1] - 1;   // reserved last slot = self-loop
        csr_src[slot] = gid;
        csr_dst[slot] = gid;
        csr_eid[slot] = E + gid;       // >= E marks self-loop
    }
}

// ---------- weight prep for MFMA edge MLP1 (factored) ----------
__global__ void conv_weights1_k(const float* __restrict__ w1, const float* __restrict__ w2,
                                short* __restrict__ w1p, short* __restrict__ w1c,
                                short* __restrict__ w2s) {
    int gid = blockIdx.x * 256 + threadIdx.x;
    if (gid < 1024) {
        int f = gid >> 6, lane = gid & 63;
        int kk = f >> 3, tt = f & 7;
        int n = tt * 16 + (lane & 15);
        int k0 = kk * 32 + (lane >> 4) * 8;
        short8 v;
        for (int j = 0; j < 8; ++j) {
            int k = k0 + j;
            float x = (n < 64) ? w1[k * 64 + n] : w1[(64 + k) * 64 + (n - 64)];
            v[j] = (short)f2bf(x);
        }
        *(short8*)(w1p + (long long)gid * 8) = v;
    } else if (gid < 1280) {
        int g2 = gid - 1024;
        int tt = g2 >> 6, lane = g2 & 63;
        int n = tt * 16 + (lane & 15);
        int k0 = (lane >> 4) * 8;
        short8 v;
        for (int j = 0; j < 8; ++j) {
            int k = k0 + j;
            v[j] = (k < 16) ? (short)f2bf(w1[(128 + k) * 64 + n]) : (short)0;
        }
        *(short8*)(w1c + (long long)g2 * 8) = v;
    } else if (gid < 2304) {
        int g2 = gid - 1280;
        int f = g2 >> 6, lane = g2 & 63;
        int kk = f >> 3, tt = f & 7;
        int n = tt * 16 + (lane & 15);
        int k0 = kk * 32 + (lane >> 4) * 8;
        short8 v;
        for (int j = 0; j < 8; ++j) v[j] = (short)f2bf(w2[(k0 + j) * 128 + n]);
        *(short8*)(w2s + (long long)g2 * 8) = v;
    }
}

// ---------- ew prep: ew[128][256] -> frags 4 kk x 16 tt ----------
__global__ void conv_ew_k(const float* __restrict__ ew, short* __restrict__ ews) {
    int gid = blockIdx.x * 256 + threadIdx.x;
    if (gid >= 4096) return;
    int f = gid >> 6, lane = gid & 63;
    int kk = f >> 4, tt = f & 15;
    int n = tt * 16 + (lane & 15);
    int k0 = kk * 32 + (lane >> 4) * 8;
    short8 v;
    for (int j = 0; j < 8; ++j) v[j] = (short)f2bf(ew[(k0 + j) * 256 + n]);
    *(short8*)(ews + (long long)gid * 8) = v;
}

// ---------- node-linear weight prep: [wl|wr] (K x 512) -> frags ----------
template <int K>
__global__ void conv_nodew_k(const float* __restrict__ wl, const float* __restrict__ wr,
                             short* __restrict__ out) {
    int gid = blockIdx.x * 256 + threadIdx.x;
    if (gid >= (K / 32) * 32 * 64) return;
    int f = gid >> 6, lane = gid & 63;
    int kk = f >> 5, tt = f & 31;
    int n = tt * 16 + (lane & 15);
    int k0 = kk * 32 + (lane >> 4) * 8;
    short8 v;
    for (int j = 0; j < 8; ++j) {
        int k = k0 + j;
        float x = (n < 256) ? wl[k * 256 + n] : wr[k * 256 + (n - 256)];
        v[j] = (short)f2bf(x);
    }
    *(short8*)(out + (long long)gid * 8) = v;
}

// ---------- pre2 weight prep ----------
__global__ void conv_pre2w_k(const float* __restrict__ w1, short* __restrict__ out) {
    int gid = blockIdx.x * 256 + threadIdx.x;
    if (gid >= 8 * 16 * 64) return;
    int f = gid >> 6, lane = gid & 63;
    int kk = f >> 4, tt = f & 15;
    int n = tt * 16 + (lane & 15);
    int k0 = kk * 32 + (lane >> 4) * 8;
    short8 v;
    for (int j = 0; j < 8; ++j) {
        int k = k0 + j;
        float x = (n < 128) ? w1[k * 128 + n] : w1[(256 + k) * 128 + (n - 128)];
        v[j] = (short)f2bf(x);
    }
    *(short8*)(out + (long long)gid * 8) = v;
}

// ---------- pre1: pre1[n] = [ x@W1a | x@W1b + b1 ]  (N x 128 bf16) ----------
__global__ __launch_bounds__(256) void pre1_mfma_k(
    const float* __restrict__ x, const short* __restrict__ w1p,
    const float* __restrict__ b1, bf16* __restrict__ pre1, int N) {
    __shared__ short At[16][72];
    __shared__ short Ot[16][136];
    int t = threadIdx.x;
    long long n0 = (long long)blockIdx.x * 16;
    {
        int r = t >> 4, c = t & 15;
        long long n = n0 + r;
        float4 v = {0.f, 0.f, 0.f, 0.f};
        if (n < N) v = *(const float4*)(x + n * 64 + c * 4);
        ushort4 pk;
        pk.x = f2bf(v.x); pk.y = f2bf(v.y); pk.z = f2bf(v.z); pk.w = f2bf(v.w);
        *(ushort4*)&At[r][c * 4] = pk;
    }
    __syncthreads();
    int w = t >> 6, lane = t & 63;
    int nq = w * 2;
    int lr = lane & 15, lq = lane >> 4;
    floatx4 acc[2];
    for (int i = 0; i < 2; ++i) acc[i] = (floatx4){0.f, 0.f, 0.f, 0.f};
    for (int kk = 0; kk < 2; ++kk) {
        short8 a = *(const short8*)&At[lr][kk * 32 + lq * 8];
        for (int tt = 0; tt < 2; ++tt) {
            short8 b = *(const short8*)(w1p + ((long long)((kk * 8 + nq + tt) * 64 + lane)) * 8);
            acc[tt] = __builtin_amdgcn_mfma_f32_16x16x32_bf16(a, b, acc[tt], 0, 0, 0);
        }
    }
    for (int tt = 0; tt < 2; ++tt) {
        int col = (nq + tt) * 16 + lr;
        float bv = (col >= 64) ? b1[col - 64] : 0.f;
        for (int r = 0; r < 4; ++r)
            Ot[lq * 4 + r][col] = (short)f2bf(acc[tt][r] + bv);
    }
    __syncthreads();
    {
        int r = t >> 4, c = t & 15;
        long long n = n0 + r;
        if (n < N)
            *(short8*)(void*)(pre1 + n * 128 + c * 8) = *(const short8*)&Ot[r][c * 8];
    }
}

// ---------- Edge MLP 1 via MFMA (swapped operands: A=weights, B=data) ----------
// acc = pre1_s[src]+pre1_d[dst](+b1) ; + ea@W1c ; relu ; @W2 ; @ews -> fp8 ee8.
// C-layout is channel-major per lane -> float4 acc-init, pk_bf16/pk_fp8 packed stores.
__global__ __launch_bounds__(256) void edge_mlp1_mfma_k(
    const bf16* __restrict__ pre1, const float* __restrict__ ea,
    const int* __restrict__ csr_src, const int* __restrict__ csr_dst,
    const int* __restrict__ csr_eid,
    const short* __restrict__ w1c,
    const short* __restrict__ w2s, const float* __restrict__ b2,
    const short* __restrict__ ews,
    unsigned char* __restrict__ ee8, int NT, int E) {
    __shared__ float Ps[32][76];         // PsA (64 chans); dead after A1 -> Et alias (32*272 B)
    __shared__ short Ae[32][40];         // ea tile: 16 valid K + 16 zero-pad
    __shared__ short Ht[32][72];         // hidden (64 chans)
    __shared__ short A2[32][136];        // ea2 tile (128 chans)
    __shared__ int sdv[32][3];
    unsigned char* Et = (unsigned char*)&Ps[0][0];
    int t = threadIdx.x;
    long long s0 = (long long)blockIdx.x * 32;
    if (t < 96) {
        int r = t & 31, which = t >> 5;
        long long s = s0 + r;
        int v = (which == 2) ? E : 0;
        if (s < NT) v = (which == 0) ? csr_src[s] : (which == 1 ? csr_dst[s] : csr_eid[s]);
        sdv[r][which] = v;
    }
    __syncthreads();
    {   // PsA init: pre1[src][0:64] + pre1[dst][64:128]
        int r = t >> 3, c = t & 7;
        long long s = s0 + r;
        bool ok = (s < NT) && (sdv[r][2] < E);
        float p[8];
        if (ok) {
            short8 vs = *(const short8*)(const void*)(pre1 + (long long)sdv[r][0] * 128 + c * 8);
            short8 vd = *(const short8*)(const void*)(pre1 + (long long)sdv[r][1] * 128 + 64 + c * 8);
            for (int j = 0; j < 8; ++j)
                p[j] = bfu((unsigned short)vs[j]) + bfu((unsigned short)vd[j]);
        } else {
            for (int j = 0; j < 8; ++j) p[j] = 0.f;
        }
        for (int j = 0; j < 8; ++j) Ps[r][c * 8 + j] = p[j];
    }
    if (t < 128) {   // ea gather: 16 floats/row
        int r = t >> 2, c = t & 3;
        long long s = s0 + r;
        int eid = sdv[r][2];
        float4 v = {0.f, 0.f, 0.f, 0.f};
        if (s < NT && eid < E) v = *(const float4*)(ea + (long long)eid * 16 + c * 4);
        ushort4 pk;
        pk.x = f2bf(v.x); pk.y = f2bf(v.y); pk.z = f2bf(v.z); pk.w = f2bf(v.w);
        *(ushort4*)&Ae[r][c * 4] = pk;
    } else {         // zero-pad K 16..31
        int i = t - 128;
        int r = i >> 2, c = i & 3;
        *(ushort4*)&Ae[r][16 + c * 4] = (ushort4){0, 0, 0, 0};
    }
    __syncthreads();

    int w = t >> 6, lane = t & 63;
    int sl = (w & 1) * 16 + (lane & 15);   // this lane's slot
    int lq = lane >> 4;

    // phase 1: h1 = relu(PsA + ea@W1c)  (64 chans, 4 m-tiles; 2 per wave)
    {
        int mb = (w >> 1) * 2;
        floatx4 acc[2];
        #pragma unroll
        for (int tt = 0; tt < 2; ++tt)
            acc[tt] = *(const floatx4*)&Ps[sl][(mb + tt) * 16 + lq * 4];
        short8 bfr = *(const short8*)&Ae[sl][lq * 8];
        #pragma unroll
        for (int tt = 0; tt < 2; ++tt) {
            short8 a = *(const short8*)(w1c + ((long long)((mb + tt) * 64 + lane)) * 8);
            acc[tt] = __builtin_amdgcn_mfma_f32_16x16x32_bf16(a, bfr, acc[tt], 0, 0, 0);
        }
        #pragma unroll
        for (int tt = 0; tt < 2; ++tt) {
            int ch0 = (mb + tt) * 16 + lq * 4;
            uint2 o;
            o.x = pk_bf16(fmaxf(acc[tt][0], 0.f), fmaxf(acc[tt][1], 0.f));
            o.y = pk_bf16(fmaxf(acc[tt][2], 0.f), fmaxf(acc[tt][3], 0.f));
            *(uint2*)&Ht[sl][ch0] = o;
        }
    }
    __syncthreads();

    // phase 2: ea2 = h1 @ W2 + b2  (128 chans, 8 m-tiles; 4 per wave)
    {
        int mb = (w >> 1) * 4;
        floatx4 acc2[4];
        #pragma unroll
        for (int i = 0; i < 4; ++i) acc2[i] = (floatx4){0.f, 0.f, 0.f, 0.f};
        #pragma unroll
        for (int kk = 0; kk < 2; ++kk) {
            short8 bfr = *(const short8*)&Ht[sl][kk * 32 + lq * 8];
            #pragma unroll
            for (int tt = 0; tt < 4; ++tt) {
                short8 a = *(const short8*)(w2s + ((long long)((kk * 8 + mb + tt) * 64 + lane)) * 8);
                acc2[tt] = __builtin_amdgcn_mfma_f32_16x16x32_bf16(a, bfr, acc2[tt], 0, 0, 0);
            }
        }
        #pragma unroll
        for (int tt = 0; tt < 4; ++tt) {
            int ch0 = (mb + tt) * 16 + lq * 4;
            float4 bv = *(const float4*)(b2 + ch0);
            uint2 o;
            o.x = pk_bf16(acc2[tt][0] + bv.x, acc2[tt][1] + bv.y);
            o.y = pk_bf16(acc2[tt][2] + bv.z, acc2[tt][3] + bv.w);
            *(uint2*)&A2[sl][ch0] = o;
        }
    }
    __syncthreads();

    // phase 3: ee = ea2 @ ews (K=128 -> 256 chans, 16 m-tiles; 8 per wave), fp8 pack into Et
    {
        int mb = (w >> 1) * 8;
        floatx4 acc3[8];
        #pragma unroll
        for (int i = 0; i < 8; ++i) acc3[i] = (floatx4){0.f, 0.f, 0.f, 0.f};
        #pragma unroll
        for (int kk = 0; kk < 4; ++kk) {
            short8 bfr = *(const short8*)&A2[sl][kk * 32 + lq * 8];
            #pragma unroll
            for (int tt = 0; tt < 8; ++tt) {
                short8 a = *(const short8*)(ews + ((long long)((kk * 16 + mb + tt) * 64 + lane)) * 8);
                acc3[tt] = __builtin_amdgcn_mfma_f32_16x16x32_bf16(a, bfr, acc3[tt], 0, 0, 0);
            }
        }
        #pragma unroll
        for (int tt = 0; tt < 8; ++tt) {
            int ch0 = (mb + tt) * 16 + lq * 4;
            unsigned u = pk_fp8x4(acc3[tt][0], acc3[tt][1], acc3[tt][2], acc3[tt][3]);
            *(unsigned*)(Et + sl * 272 + ch0) = u;
        }
    }
    __syncthreads();
    for (int i = t; i < 512; i += 256) {
        int r = i >> 4, c = i & 15;
        long long s = s0 + r;
        if (s < NT)
            *(uint4*)(ee8 + s * 256 + c * 16) = *(const uint4*)(Et + r * 272 + c * 16);
    }
}

// ---------- node linear via MFMA (swapped operands): [N x K] @ [K x 512] + bias ----------
// NOTE: x may alias xr (x1bn overlay) — per-block reads complete before same-row writes.
template <int K, typename T>
__global__ __launch_bounds__(256) void node_linear_mfma_k(
    const T* x, const short* __restrict__ ws,
    const float* __restrict__ bl, const float* __restrict__ br,
    bf16* __restrict__ xl, bf16* xr, int N) {
    __shared__ short At[16][K + 8];
    __shared__ short Ot[16][520];
    int t = threadIdx.x;
    long long n0 = (long long)blockIdx.x * 16;
    if (sizeof(T) == 4) {
        for (int i = t; i < 16 * (K / 4); i += 256) {
            int r = i / (K / 4), c = i % (K / 4);
            long long n = n0 + r;
            float4 v = {0.f, 0.f, 0.f, 0.f};
            if (n < N) v = *(const float4*)((const float*)x + n * K + c * 4);
            ushort4 pk;
            pk.x = f2bf(v.x); pk.y = f2bf(v.y); pk.z = f2bf(v.z); pk.w = f2bf(v.w);
            *(ushort4*)&At[r][c * 4] = pk;
        }
    } else {
        for (int i = t; i < 16 * (K / 8); i += 256) {
            int r = i / (K / 8), c = i % (K / 8);
            long long n = n0 + r;
            short8 v = {0, 0, 0, 0, 0, 0, 0, 0};
            if (n < N) v = *(const short8*)(const void*)((const bf16*)x + n * K + c * 8);
            *(short8*)&At[r][c * 8] = v;
        }
    }
    __syncthreads();

    int w = t >> 6, lane = t & 63;
    int nr = lane & 15, lq = lane >> 4;

    floatx4 acc[8];
    #pragma unroll
    for (int i = 0; i < 8; ++i) acc[i] = (floatx4){0.f, 0.f, 0.f, 0.f};
    for (int kk = 0; kk < K / 32; ++kk) {
        short8 bfr = *(const short8*)&At[nr][kk * 32 + lq * 8];
        #pragma unroll
        for (int tt = 0; tt < 8; ++tt) {
            short8 a = *(const short8*)(ws + ((long long)((kk * 32 + w * 8 + tt) * 64 + lane)) * 8);
            acc[tt] = __builtin_amdgcn_mfma_f32_16x16x32_bf16(a, bfr, acc[tt], 0, 0, 0);
        }
    }
    #pragma unroll
    for (int tt = 0; tt < 8; ++tt) {
        int ch0 = (w * 8 + tt) * 16 + lq * 4;
        const float* bp = (ch0 < 256) ? (bl + ch0) : (br + (ch0 - 256));
        float4 bv = *(const float4*)bp;
        uint2 o;
        o.x = pk_bf16(acc[tt][0] + bv.x, acc[tt][1] + bv.y);
        o.y = pk_bf16(acc[tt][2] + bv.z, acc[tt][3] + bv.w);
        *(uint2*)&Ot[nr][ch0] = o;
    }
    __syncthreads();
    for (int i = t; i < 1024; i += 256) {
        int r = i >> 6, c = i & 63;
        long long n = n0 + r;
        if (n < N) {
            short8 v = *(const short8*)&Ot[r][c * 8];
            if (c < 32) *(short8*)(void*)(xl + n * 256 + c * 8) = v;
            else        *(short8*)(void*)(xr + n * 256 + (c - 32) * 8) = v;
        }
    }
}

// ---------- pre2 (swapped operands): xp = x1bn @ M[256x256] + b1x -> xl ----------
__global__ __launch_bounds__(256) void pre_mfma_k(
    const bf16* __restrict__ x, const short* __restrict__ ws,
    const float* __restrict__ bx, bf16* __restrict__ out, int N) {
    __shared__ short At[16][264];
    __shared__ short Ot[16][264];
    int t = threadIdx.x;
    long long n0 = (long long)blockIdx.x * 16;
    for (int i = t; i < 512; i += 256) {
        int r = i >> 5, c = i & 31;
        long long n = n0 + r;
        short8 v = {0, 0, 0, 0, 0, 0, 0, 0};
        if (n < N) v = *(const short8*)(const void*)(x + n * 256 + c * 8);
        *(short8*)&At[r][c * 8] = v;
    }
    __syncthreads();

    int w = t >> 6, lane = t & 63;
    int nr = lane & 15, lq = lane >> 4;

    floatx4 acc[4];
    #pragma unroll
    for (int i = 0; i < 4; ++i) acc[i] = (floatx4){0.f, 0.f, 0.f, 0.f};
    for (int kk = 0; kk < 8; ++kk) {
        short8 bfr = *(const short8*)&At[nr][kk * 32 + lq * 8];
        #pragma unroll
        for (int tt = 0; tt < 4; ++tt) {
            short8 a = *(const short8*)(ws + ((long long)((kk * 16 + w * 4 + tt) * 64 + lane)) * 8);
            acc[tt] = __builtin_amdgcn_mfma_f32_16x16x32_bf16(a, bfr, acc[tt], 0, 0, 0);
        }
    }
    #pragma unroll
    for (int tt = 0; tt < 4; ++tt) {
        int ch0 = (w * 4 + tt) * 16 + lq * 4;
        float4 bv = *(const float4*)(bx + ch0);
        uint2 o;
        o.x = pk_bf16(acc[tt][0] + bv.x, acc[tt][1] + bv.y);
        o.y = pk_bf16(acc[tt][2] + bv.z, acc[tt][3] + bv.w);
        *(uint2*)&Ot[nr][ch0] = o;
    }
    __syncthreads();
    for (int i = t; i < 512; i += 256) {
        int r = i >> 5, c = i & 31;
        long long n = n0 + r;
        if (n < N)
            *(short8*)(void*)(out + n * 256 + c * 8) = *(const short8*)&Ot[r][c * 8];
    }
}

// ---------- Fused GATv2 attention + aggregation + finalize ----------
// Depth-2 data prefetch (xl/ee8) + depth-3 index prefetch (csr_src); ee8 reads
// are non-temporal (each row consumed exactly once, keep L2 for xl re-use).
template <bool L1>
__global__ __launch_bounds__(256) void gat_fused_k(
    const unsigned char* __restrict__ ee8, const bf16* __restrict__ xl, const bf16* xr,
    const int* __restrict__ off, const int* __restrict__ csr_src,
    const float* __restrict__ att, const float* __restrict__ bias,
    const float* __restrict__ bng, const float* __restrict__ bnb,
    const int* __restrict__ batch,
    bf16* x1bn, float* __restrict__ pooled, int N) {
    __shared__ float ps[4][260];
    __shared__ int bid[4];
    int t = threadIdx.x;
    int w = t >> 6, lane = t & 63;
    int n = blockIdx.x * 4 + w;
    bool valid = n < N;
    int c0 = lane * 4;
    float o0 = 0.f, o1 = 0.f, o2 = 0.f, o3 = 0.f;
    if (valid) {
        ushort4 xrp = *(const ushort4*)(const void*)(xr + (long long)n * 256 + c0);
        ushort4 xop = *(const ushort4*)(const void*)(xl + (long long)n * 256 + c0);
        float xr0 = bfu(xrp.x), xr1 = bfu(xrp.y), xr2 = bfu(xrp.z), xr3 = bfu(xrp.w);
        float4 atv = *(const float4*)(att + c0);
        float a0 = 0.f, a1 = 0.f, a2 = 0.f, a3 = 0.f, dacc = 0.f;
        float es0 = 0.f, es1 = 0.f, es2 = 0.f, es3 = 0.f;
        int beg = off[n], end1 = off[n + 1] - 1;   // [beg, end1) = real edges; end1 = self-loop
        // prefetch pipeline: data depth 2, index depth 3
        ushort4 xlp0, xlp1 = {0, 0, 0, 0};
        unsigned ep0 = 0, ep1 = 0;
        {
            int sid = csr_src[beg];   // valid even for deg-0 (self-loop slot)
            xlp0 = *(const ushort4*)(const void*)(xl + (long long)sid * 256 + c0);
            ep0 = __builtin_nontemporal_load((const unsigned*)(ee8 + (long long)beg * 256 + c0));
        }
        if (beg + 1 < end1) {
            int sid = csr_src[beg + 1];
            xlp1 = *(const ushort4*)(const void*)(xl + (long long)sid * 256 + c0);
            ep1 = __builtin_nontemporal_load((const unsigned*)(ee8 + (long long)(beg + 1) * 256 + c0));
        }
        int sid2 = (beg + 2 < end1) ? csr_src[beg + 2] : 0;
        for (int i = beg; i < end1; ++i) {
            ushort4 cx = xlp0;
            unsigned ce = ep0;
            xlp0 = xlp1; ep0 = ep1;
            if (i + 2 < end1) {
                xlp1 = *(const ushort4*)(const void*)(xl + (long long)sid2 * 256 + c0);
                ep1 = __builtin_nontemporal_load((const unsigned*)(ee8 + (long long)(i + 2) * 256 + c0));
                sid2 = (i + 3 < end1) ? csr_src[i + 3] : 0;
            }
            float x0 = bfu(cx.x), x1 = bfu(cx.y), x2 = bfu(cx.z), x3 = bfu(cx.w);
            float e0 = fp82f(ce & 0xff);
            float e1 = fp82f((ce >> 8) & 0xff);
            float e2 = fp82f((ce >> 16) & 0xff);
            float e3 = fp82f(ce >> 24);
            es0 += e0; es1 += e1; es2 += e2; es3 += e3;
            float m0 = x0 + xr0 + e0;
            float m1 = x1 + xr1 + e1;
            float m2 = x2 + xr2 + e2;
            float m3 = x3 + xr3 + e3;
            m0 = m0 > 0.f ? m0 : 0.2f * m0;
            m1 = m1 > 0.f ? m1 : 0.2f * m1;
            m2 = m2 > 0.f ? m2 : 0.2f * m2;
            m3 = m3 > 0.f ? m3 : 0.2f * m3;
            float p = atv.x * m0 + atv.y * m1 + atv.z * m2 + atv.w * m3;
            p += __shfl_xor(p, 1, 64);
            p += __shfl_xor(p, 2, 64);
            p += __shfl_xor(p, 4, 64);
            p += __shfl_xor(p, 8, 64);
            float ex = expf(p);
            a0 += ex * x0; a1 += ex * x1; a2 += ex * x2; a3 += ex * x3;
            dacc += ex;
        }
        // self-loop term: edge feature = mean of incoming ee
        {
            float rdv = 1.f / fmaxf((float)(end1 - beg), 1.f);
            float x0 = bfu(xop.x), x1 = bfu(xop.y), x2 = bfu(xop.z), x3 = bfu(xop.w);
            float m0 = x0 + xr0 + es0 * rdv;
            float m1 = x1 + xr1 + es1 * rdv;
            float m2 = x2 + xr2 + es2 * rdv;
            float m3 = x3 + xr3 + es3 * rdv;
            m0 = m0 > 0.f ? m0 : 0.2f * m0;
            m1 = m1 > 0.f ? m1 : 0.2f * m1;
            m2 = m2 > 0.f ? m2 : 0.2f * m2;
            m3 = m3 > 0.f ? m3 : 0.2f * m3;
            float p = atv.x * m0 + atv.y * m1 + atv.z * m2 + atv.w * m3;
            p += __shfl_xor(p, 1, 64);
            p += __shfl_xor(p, 2, 64);
            p += __shfl_xor(p, 4, 64);
            p += __shfl_xor(p, 8, 64);
            float ex = expf(p);
            a0 += ex * x0; a1 += ex * x1; a2 += ex * x2; a3 += ex * x3;
            dacc += ex;
        }
        float inv = 1.f / dacc;
        o0 = fmaxf(a0 * inv + bias[c0],     0.f);
        o1 = fmaxf(a1 * inv + bias[c0 + 1], 0.f);
        o2 = fmaxf(a2 * inv + bias[c0 + 2], 0.f);
        o3 = fmaxf(a3 * inv + bias[c0 + 3], 0.f);
        if (L1) {
            ushort4 o;
            o.x = f2bf(bng[c0]     * (o0 * INVS) + bnb[c0]);
            o.y = f2bf(bng[c0 + 1] * (o1 * INVS) + bnb[c0 + 1]);
            o.z = f2bf(bng[c0 + 2] * (o2 * INVS) + bnb[c0 + 2]);
            o.w = f2bf(bng[c0 + 3] * (o3 * INVS) + bnb[c0 + 3]);
            *(ushort4*)(void*)(x1bn + (long long)n * 256 + c0) = o;
        }
    }
    if (lane == 0) bid[w] = valid ? batch[n] : -1;
    ps[w][c0]     = o0;
    ps[w][c0 + 1] = o1;
    ps[w][c0 + 2] = o2;
    ps[w][c0 + 3] = o3;
    __syncthreads();
    int b0 = bid[0];
    bool same = (b0 >= 0)
             && (bid[1] < 0 || bid[1] == b0)
             && (bid[2] < 0 || bid[2] == b0)
             && (bid[3] < 0 || bid[3] == b0);
    if (same) {
        float s = ps[0][t] + ps[1][t] + ps[2][t] + ps[3][t];
        atomicAdd(&pooled[(long long)b0 * 256 + t], s);
    } else if (valid) {
        long long pb = (long long)bid[w] * 256 + c0;
        atomicAdd(&pooled[pb],     o0);
        atomicAdd(&pooled[pb + 1], o1);
        atomicAdd(&pooled[pb + 2], o2);
        atomicAdd(&pooled[pb + 3], o3);
    }
}

// ---------- global MLP layer1 ----------
__global__ void global_mlp1_k(const float* __restrict__ pooled,
                              const float* __restrict__ w1, const float* __restrict__ b1,
                              const float* __restrict__ w2, const float* __restrict__ b2,
                              const float* __restrict__ bng, const float* __restrict__ bnb,
                              float* __restrict__ u1bn) {
    __shared__ float pr[256];
    __shared__ float h[256];
    int t = threadIdx.x, g = blockIdx.x;
    pr[t] = pooled[g * 256 + t];
    __syncthreads();
    float acc = b1[t];
    for (int k = 0; k < 256; ++k) acc += pr[k] * w1[(256 + k) * 256 + t];
    h[t] = fmaxf(acc, 0.f);
    __syncthreads();
    float a2 = b2[t];
    for (int k = 0; k < 256; ++k) a2 += h[k] * w2[k * 256 + t];
    u1bn[g * 256 + t] = bng[t] * (a2 * INVS) + bnb[t];
}

// ---------- weight prep for MFMA edge MLP2 (+ b1x for pre path) ----------
__global__ void conv_weights_k(const float* __restrict__ w1, const float* __restrict__ w2,
                               const float* __restrict__ b1,
                               const float* __restrict__ bg, const float* __restrict__ bb,
                               short* __restrict__ w1s, short* __restrict__ w2s,
                               float* __restrict__ b1x) {
    int gid = blockIdx.x * 256 + threadIdx.x;
    if (gid < 10240) {
        int f = gid >> 6, lane = gid & 63;
        int kk = f >> 3, tt = f & 7;
        int n = tt * 16 + (lane & 15);
        int k0 = kk * 32 + (lane >> 4) * 8;
        short8 v;
        for (int j = 0; j < 8; ++j) {
            int k = k0 + j;
            float x = w1[k * 128 + n];
            if (k >= 512) x *= bg[k - 512] * INVS;
            v[j] = (short)f2bf(x);
        }
        *(short8*)(w1s + (long long)gid * 8) = v;
    } else if (gid < 12288) {
        int g2 = gid - 10240;
        int f = g2 >> 6, lane = g2 & 63;
        int kk = f >> 3, tt = f & 7;
        int n = tt * 16 + (lane & 15);
        int k0 = kk * 32 + (lane >> 4) * 8;
        short8 v;
        for (int j = 0; j < 8; ++j) v[j] = (short)f2bf(w2[(k0 + j) * 128 + n]);
        *(short8*)(w2s + (long long)g2 * 8) = v;
    } else if (gid < 12544) {
        int j = gid - 12288;
        b1x[j] = 0.f;
    } else if (gid < 12672) {
        int j = gid - 12544;
        float acc = b1[j];
        for (int c = 0; c < 128; ++c) acc += bb[c] * w1[(512 + c) * 128 + j];
        b1x[128 + j] = acc;
    }
}

// ---------- Edge MLP 2 via MFMA (swapped operands), fused with ee-GEMM; ea2 recomputed ----------
__global__ __launch_bounds__(256) void edge_mlp2_mfma_k(
    const bf16* __restrict__ xpre, const bf16* __restrict__ pre1,
    const float* __restrict__ ea,
    const int* __restrict__ csr_src, const int* __restrict__ csr_dst,
    const int* __restrict__ csr_eid,
    const short* __restrict__ w1c, const short* __restrict__ w2s1,
    const float* __restrict__ e1_b2,
    const short* __restrict__ w1s,       // uses kk 16..19 (ea rows, BN-folded)
    const short* __restrict__ w2s, const float* __restrict__ b2,
    const short* __restrict__ ews,
    unsigned char* __restrict__ ee8, int NT, int E) {
    __shared__ float Ps[32][140];        // PsA (64) -> PsB (128) -> Et (fp8 tile, 32*272 B)
    __shared__ short At[32][136];
    __shared__ short Ht[32][136];
    __shared__ short Ae[32][40];
    __shared__ int sdv[32][3];
    unsigned char* Et = (unsigned char*)&Ps[0][0];
    int t = threadIdx.x;
    long long s0 = (long long)blockIdx.x * 32;
    if (t < 96) {
        int r = t & 31, which = t >> 5;
        long long s = s0 + r;
        int v = (which == 2) ? E : 0;
        if (s < NT) v = (which == 0) ? csr_src[s] : (which == 1 ? csr_dst[s] : csr_eid[s]);
        sdv[r][which] = v;
    }
    __syncthreads();
    {   // PsA init: pre1[src][0:64] + pre1[dst][64:128]
        int r = t >> 3, c = t & 7;
        long long s = s0 + r;
        bool ok = (s < NT) && (sdv[r][2] < E);
        float p[8];
        if (ok) {
            short8 vs = *(const short8*)(const void*)(pre1 + (long long)sdv[r][0] * 128 + c * 8);
            short8 vd = *(const short8*)(const void*)(pre1 + (long long)sdv[r][1] * 128 + 64 + c * 8);
            for (int j = 0; j < 8; ++j)
                p[j] = bfu((unsigned short)vs[j]) + bfu((unsigned short)vd[j]);
        } else {
            for (int j = 0; j < 8; ++j) p[j] = 0.f;
        }
        for (int j = 0; j < 8; ++j) Ps[r][c * 8 + j] = p[j];
    }
    if (t < 128) {   // ea gather
        int r = t >> 2, c = t & 3;
        long long s = s0 + r;
        int eid = sdv[r][2];
        float4 v = {0.f, 0.f, 0.f, 0.f};
        if (s < NT && eid < E) v = *(const float4*)(ea + (long long)eid * 16 + c * 4);
        ushort4 pk;
        pk.x = f2bf(v.x); pk.y = f2bf(v.y); pk.z = f2bf(v.z); pk.w = f2bf(v.w);
        *(ushort4*)&Ae[r][c * 4] = pk;
    } else {
        int i = t - 128;
        int r = i >> 2, c = i & 3;
        *(ushort4*)&Ae[r][16 + c * 4] = (ushort4){0, 0, 0, 0};
    }
    __syncthreads();

    int w = t >> 6, lane = t & 63;
    int sl = (w & 1) * 16 + (lane & 15);
    int lq = lane >> 4;

    // phase A1: h1 = relu(PsA + ea@W1c)  (64 chans)
    {
        int mb = (w >> 1) * 2;
        floatx4 acc[2];
        #pragma unroll
        for (int tt = 0; tt < 2; ++tt)
            acc[tt] = *(const floatx4*)&Ps[sl][(mb + tt) * 16 + lq * 4];
        short8 bfr = *(const short8*)&Ae[sl][lq * 8];
        #pragma unroll
        for (int tt = 0; tt < 2; ++tt) {
            short8 a = *(const short8*)(w1c + ((long long)((mb + tt) * 64 + lane)) * 8);
            acc[tt] = __builtin_amdgcn_mfma_f32_16x16x32_bf16(a, bfr, acc[tt], 0, 0, 0);
        }
        #pragma unroll
        for (int tt = 0; tt < 2; ++tt) {
            int ch0 = (mb + tt) * 16 + lq * 4;
            uint2 o;
            o.x = pk_bf16(fmaxf(acc[tt][0], 0.f), fmaxf(acc[tt][1], 0.f));
            o.y = pk_bf16(fmaxf(acc[tt][2], 0.f), fmaxf(acc[tt][3], 0.f));
            *(uint2*)&Ht[sl][ch0] = o;
        }
    }
    __syncthreads();

    // PsB init (pre2 gathers, overlaps A2 compute)
    for (int i = t; i < 512; i += 256) {
        int r = i >> 4, c = i & 15;
        long long s = s0 + r;
        bool ok = (s < NT) && (sdv[r][2] < E);
        float p[8];
        if (ok) {
            short8 vs = *(const short8*)(const void*)(xpre + (long long)sdv[r][0] * 256 + c * 8);
            short8 vd = *(const short8*)(const void*)(xpre + (long long)sdv[r][1] * 256 + 128 + c * 8);
            for (int j = 0; j < 8; ++j)
                p[j] = bfu((unsigned short)vs[j]) + bfu((unsigned short)vd[j]);
        } else {
            for (int j = 0; j < 8; ++j) p[j] = 0.f;
        }
        for (int j = 0; j < 8; ++j) Ps[r][c * 8 + j] = p[j];
    }
    // phase A2: ea2 = h1@W2s1 + e1_b2 -> At  (128 chans)
    {
        int mb = (w >> 1) * 4;
        floatx4 acc2[4];
        #pragma unroll
        for (int i = 0; i < 4; ++i) acc2[i] = (floatx4){0.f, 0.f, 0.f, 0.f};
        #pragma unroll
        for (int kk = 0; kk < 2; ++kk) {
            short8 bfr = *(const short8*)&Ht[sl][kk * 32 + lq * 8];
            #pragma unroll
            for (int tt = 0; tt < 4; ++tt) {
                short8 a = *(const short8*)(w2s1 + ((long long)((kk * 8 + mb + tt) * 64 + lane)) * 8);
                acc2[tt] = __builtin_amdgcn_mfma_f32_16x16x32_bf16(a, bfr, acc2[tt], 0, 0, 0);
            }
        }
        #pragma unroll
        for (int tt = 0; tt < 4; ++tt) {
            int ch0 = (mb + tt) * 16 + lq * 4;
            float4 bv = *(const float4*)(e1_b2 + ch0);
            uint2 o;
            o.x = pk_bf16(acc2[tt][0] + bv.x, acc2[tt][1] + bv.y);
            o.y = pk_bf16(acc2[tt][2] + bv.z, acc2[tt][3] + bv.w);
            *(uint2*)&At[sl][ch0] = o;
        }
    }
    __syncthreads();

    // phase B1: h = relu(PsB + ea2@W1s[kk16..19])  (128 chans)
    {
        int mb = (w >> 1) * 4;
        floatx4 acc[4];
        #pragma unroll
        for (int tt = 0; tt < 4; ++tt)
            acc[tt] = *(const floatx4*)&Ps[sl][(mb + tt) * 16 + lq * 4];
        #pragma unroll
        for (int kk = 0; kk < 4; ++kk) {
            short8 bfr = *(const short8*)&At[sl][kk * 32 + lq * 8];
            #pragma unroll
            for (int tt = 0; tt < 4; ++tt) {
                short8 a = *(const short8*)(w1s + ((long long)(((16 + kk) * 8 + mb + tt) * 64 + lane)) * 8);
                acc[tt] = __builtin_amdgcn_mfma_f32_16x16x32_bf16(a, bfr, acc[tt], 0, 0, 0);
            }
        }
        #pragma unroll
        for (int tt = 0; tt < 4; ++tt) {
            int ch0 = (mb + tt) * 16 + lq * 4;
            uint2 o;
            o.x = pk_bf16(fmaxf(acc[tt][0], 0.f), fmaxf(acc[tt][1], 0.f));
            o.y = pk_bf16(fmaxf(acc[tt][2], 0.f), fmaxf(acc[tt][3], 0.f));
            *(uint2*)&Ht[sl][ch0] = o;
        }
    }
    __syncthreads();

    // phase B2: ea2' = h @ W2 + b2 -> At  (128 chans)
    {
        int mb = (w >> 1) * 4;
        floatx4 acc2[4];
        #pragma unroll
        for (int i = 0; i < 4; ++i) acc2[i] = (floatx4){0.f, 0.f, 0.f, 0.f};
        #pragma unroll
        for (int kk = 0; kk < 4; ++kk) {
            short8 bfr = *(const short8*)&Ht[sl][kk * 32 + lq * 8];
            #pragma unroll
            for (int tt = 0; tt < 4; ++tt) {
                short8 a = *(const short8*)(w2s + ((long long)((kk * 8 + mb + tt) * 64 + lane)) * 8);
                acc2[tt] = __builtin_amdgcn_mfma_f32_16x16x32_bf16(a, bfr, acc2[tt], 0, 0, 0);
            }
        }
        #pragma unroll
        for (int tt = 0; tt < 4; ++tt) {
            int ch0 = (mb + tt) * 16 + lq * 4;
            float4 bv = *(const float4*)(b2 + ch0);
            uint2 o;
            o.x = pk_bf16(acc2[tt][0] + bv.x, acc2[tt][1] + bv.y);
            o.y = pk_bf16(acc2[tt][2] + bv.z, acc2[tt][3] + bv.w);
            *(uint2*)&At[sl][ch0] = o;
        }
    }
    __syncthreads();

    // phase B3: ee = ea2' @ ews (K=128 -> 256 chans), fp8 pack into Et (aliases dead Ps)
    {
        int mb = (w >> 1) * 8;
        floatx4 acc3[8];
        #pragma unroll
        for (int i = 0; i < 8; ++i) acc3[i] = (floatx4){0.f, 0.f, 0.f, 0.f};
        #pragma unroll
        for (int kk = 0; kk < 4; ++kk) {
            short8 bfr = *(const short8*)&At[sl][kk * 32 + lq * 8];
            #pragma unroll
            for (int tt = 0; tt < 8; ++tt) {
                short8 a = *(const short8*)(ews + ((long long)((kk * 16 + mb + tt) * 64 + lane)) * 8);
                acc3[tt] = __builtin_amdgcn_mfma_f32_16x16x32_bf16(a, bfr, acc3[tt], 0, 0, 0);
            }
        }
        #pragma unroll
        for (int tt = 0; tt < 8; ++tt) {
            int ch0 = (mb + tt) * 16 + lq * 4;
            unsigned u = pk_fp8x4(acc3[tt][0], acc3[tt][1], acc3[tt][2], acc3[tt][3]);
            *(unsigned*)(Et + sl * 272 + ch0) = u;
        }
    }
    __syncthreads();
    for (int i = t; i < 512; i += 256) {
        int r = i >> 4, c = i & 15;
        long long s = s0 + r;
        if (s < NT && sdv[r][2] < E)
            *(uint4*)(ee8 + s * 256 + c * 16) = *(const uint4*)(Et + r * 272 + c * 16);
    }
}

// ---------- final global MLP + head ----------
__global__ void final_mlp_k(const float* __restrict__ u1bn, const float* __restrict__ pooled,
                            const float* __restrict__ w1, const float* __restrict__ b1,
                            const float* __restrict__ w2, const float* __restrict__ b2,
                            const float* __restrict__ f1w, const float* __restrict__ f1b,
                            const float* __restrict__ f2w, const float* __restrict__ f2b,
                            float* __restrict__ out) {
    __shared__ float ub[256], pb[256], h[256], u2[256];
    int t = threadIdx.x, g = blockIdx.x;
    ub[t] = u1bn[g * 256 + t];
    pb[t] = pooled[g * 256 + t];
    __syncthreads();
    float acc = b1[t];
    for (int k = 0; k < 256; ++k)
        acc += ub[k] * w1[k * 256 + t] + pb[k] * w1[(256 + k) * 256 + t];
    h[t] = fmaxf(acc, 0.f);
    __syncthreads();
    float a2 = b2[t];
    for (int k = 0; k < 256; ++k) a2 += h[k] * w2[k * 256 + t];
    u2[t] = a2;
    __syncthreads();
    float fv = 0.f;
    if (t < 64) {
        float a3 = f1b[t];
        for (int k = 0; k < 256; ++k) a3 += u2[k] * f1w[k * 64 + t];
        fv = fmaxf(a3, 0.f) * f2w[t];
    }
    for (int off = 32; off; off >>= 1) fv += __shfl_down(fv, off, 64);
    if (t == 0) out[g] = fv + f2b[0];
}

// ---------- launch ----------
extern "C" void kernel_launch(void* const* d_in, const int* in_sizes, int n_in,
                              void* d_out, int out_size, void* d_ws, size_t ws_size,
                              hipStream_t stream) {
    const float* x         = (const float*)d_in[0];
    const float* edge_attr = (const float*)d_in[1];
    const float* e1_w1 = (const float*)d_in[2];
    const float* e1_b1 = (const float*)d_in[3];
    const float* e1_w2 = (const float*)d_in[4];
    const float* e1_b2 = (const float*)d_in[5];
    const float* g1_lw = (const float*)d_in[6];
    const float* g1_lb = (const float*)d_in[7];
    const float* g1_rw = (const float*)d_in[8];
    const float* g1_rb = (const float*)d_in[9];
    const float* g1_ew = (const float*)d_in[10];
    const float* g1_att = (const float*)d_in[11];
    const float* g1_bias = (const float*)d_in[12];
    const float* u1_w1 = (const float*)d_in[13];
    const float* u1_b1 = (const float*)d_in[14];
    const float* u1_w2 = (const float*)d_in[15];
    const float* u1_b2 = (const float*)d_in[16];
    const float* bn_n_g = (const float*)d_in[17];
    const float* bn_n_b = (const float*)d_in[18];
    const float* bn_e_g = (const float*)d_in[19];
    const float* bn_e_b = (const float*)d_in[20];
    const float* bn_u_g = (const float*)d_in[21];
    const float* bn_u_b = (const float*)d_in[22];
    const float* e2_w1 = (const float*)d_in[23];
    const float* e2_b1 = (const float*)d_in[24];
    const float* e2_w2 = (const float*)d_in[25];
    const float* e2_b2 = (const float*)d_in[26];
    const float* g2_lw = (const float*)d_in[27];
    const float* g2_lb = (const float*)d_in[28];
    const float* g2_rw = (const float*)d_in[29];
    const float* g2_rb = (const float*)d_in[30];
    const float* g2_ew = (const float*)d_in[31];
    const float* g2_att = (const float*)d_in[32];
    const float* g2_bias = (const float*)d_in[33];
    const float* u2_w1 = (const float*)d_in[34];
    const float* u2_b1 = (const float*)d_in[35];
    const float* u2_w2 = (const float*)d_in[36];
    const float* u2_b2 = (const float*)d_in[37];
    const float* fc1_w = (const float*)d_in[38];
    const float* fc1_b = (const float*)d_in[39];
    const float* fc2_w = (const float*)d_in[40];
    const float* fc2_b = (const float*)d_in[41];
    const int* edge_index = (const int*)d_in[42];
    const int* batch = (const int*)d_in[43];

    const int N = in_sizes[0] / 64;
    const int E = in_sizes[1] / 16;
    const int NT = E + N;
    const int G = G_GRAPHS;
    const int* src = edge_index;
    const int* dst = edge_index + E;
    const int NB = (NT + 31) / 32;
    const int NSB = (N + 2047) / 2048;   // scan blocks

    // workspace carve (x1bn aliases xr; pre2 lives in xl during edge_mlp2)
    char* p = (char*)d_ws;
    auto alloc = [&](size_t bytes) { char* r = p; p += (bytes + 255) & ~(size_t)255; return r; };
    bf16* xl    = (bf16*)alloc((size_t)N * 256 * 2);
    bf16* xr    = (bf16*)alloc((size_t)N * 256 * 2);
    bf16* x1bn  = xr;
    unsigned char* ee8 = (unsigned char*)alloc((size_t)NT * 256);
    bf16* pre1  = (bf16*)alloc((size_t)N * 128 * 2);
    int* degi   = (int*)alloc((size_t)N * 4);
    int* off    = (int*)alloc((size_t)(N + 1) * 4);
    int* fillc  = (int*)alloc((size_t)N * 4);
    int* csr_src = (int*)alloc((size_t)NT * 4);
    int* csr_dst = (int*)alloc((size_t)NT * 4);
    int* csr_eid = (int*)alloc((size_t)NT * 4);
    int* bsum   = (int*)alloc((size_t)(NSB + 1) * 4);
    int* boff   = (int*)alloc((size_t)(NSB + 1) * 4);
    float* pooled = (float*)alloc((size_t)G * 256 * 4);
    float* u1bn = (float*)alloc((size_t)G * 256 * 4);
    short* w1s  = (short*)alloc((size_t)20 * 8 * 64 * 8 * 2);
    short* w2s  = (short*)alloc((size_t)4 * 8 * 64 * 8 * 2);
    float* b1x  = (float*)alloc((size_t)256 * 4);
    short* w1p  = (short*)alloc((size_t)16 * 64 * 8 * 2);
    short* w1c  = (short*)alloc((size_t)4 * 64 * 8 * 2);
    short* w2s1 = (short*)alloc((size_t)16 * 64 * 8 * 2);
    short* ews1 = (short*)alloc((size_t)4 * 16 * 64 * 8 * 2);
    short* ews2 = (short*)alloc((size_t)4 * 16 * 64 * 8 * 2);
    short* nw1  = (short*)alloc((size_t)2 * 32 * 64 * 8 * 2);
    short* nw2  = (short*)alloc((size_t)8 * 32 * 64 * 8 * 2);
    short* nwp  = (short*)alloc((size_t)8 * 16 * 64 * 8 * 2);

    // ===== CSR build =====
    hipMemsetAsync(degi, 0, (size_t)N * 4, stream);
    hipMemsetAsync(fillc, 0, (size_t)N * 4, stream);
    hipMemsetAsync(pooled, 0, (size_t)G * 256 * 4, stream);
    degi_k<<<(E + 255) / 256, 256, 0, stream>>>(dst, degi, E);
    scan_blk_k<<<NSB, 1024, 0, stream>>>(degi, off, bsum, N);
    scan_top_k<<<1, 64, 0, stream>>>(bsum, boff, off, NSB, N);
    scan_add_k<<<(N + 255) / 256, 256, 0, stream>>>(off, boff, N);
    fill_csr_k<<<(max(E, N) + 255) / 256, 256, 0, stream>>>(src, dst, off, fillc,
                                                            csr_src, csr_dst, csr_eid, E, N);

    // ===== layer 1 =====
    conv_weights1_k<<<9, 256, 0, stream>>>(e1_w1, e1_w2, w1p, w1c, w2s1);
    conv_ew_k<<<16, 256, 0, stream>>>(g1_ew, ews1);
    conv_ew_k<<<16, 256, 0, stream>>>(g2_ew, ews2);
    conv_nodew_k<64><<<16, 256, 0, stream>>>(g1_lw, g1_rw, nw1);
    conv_nodew_k<256><<<64, 256, 0, stream>>>(g2_lw, g2_rw, nw2);
    conv_pre2w_k<<<32, 256, 0, stream>>>(e2_w1, nwp);
    pre1_mfma_k<<<(N + 15) / 16, 256, 0, stream>>>(x, w1p, e1_b1, pre1, N);
    edge_mlp1_mfma_k<<<NB, 256, 0, stream>>>(pre1, edge_attr, csr_src, csr_dst, csr_eid,
                                             w1c, w2s1, e1_b2, ews1, ee8, NT, E);
    node_linear_mfma_k<64, float><<<(N + 15) / 16, 256, 0, stream>>>(x, nw1, g1_lb, g1_rb, xl, xr, N);
    gat_fused_k<true><<<(N + 3) / 4, 256, 0, stream>>>(ee8, xl, xr, off, csr_src,
                                                       g1_att, g1_bias, bn_n_g, bn_n_b,
                                                       batch, x1bn, pooled, N);
    global_mlp1_k<<<G, 256, 0, stream>>>(pooled, u1_w1, u1_b1, u1_w2, u1_b2, bn_u_g, bn_u_b, u1bn);

    // ===== layer 2 =====
    conv_weights_k<<<50, 256, 0, stream>>>(e2_w1, e2_w2, e2_b1, bn_e_g, bn_e_b, w1s, w2s, b1x);
    pre_mfma_k<<<(N + 15) / 16, 256, 0, stream>>>(x1bn, nwp, b1x, xl, N);
    edge_mlp2_mfma_k<<<NB, 256, 0, stream>>>(xl, pre1, edge_attr, csr_src, csr_dst, csr_eid,
                                             w1c, w2s1, e1_b2, w1s, w2s, e2_b2, ews2,
                                             ee8, NT, E);
    node_linear_mfma_k<256, bf16><<<(N + 15) / 16, 256, 0, stream>>>(x1bn, nw2, g2_lb, g2_rb, xl, xr, N);
    hipMemsetAsync(pooled, 0, (size_t)G * 256 * 4, stream);
    gat_fused_k<false><<<(N + 3) / 4, 256, 0, stream>>>(ee8, xl, xr, off, csr_src,
                                                        g2_att, g2_bias, nullptr, nullptr,
                                                        batch, nullptr, pooled, N);
    final_mlp_k<<<G, 256, 0, stream>>>(u1bn, pooled, u2_w1, u2_b1, u2_w2, u2_b2,
                                       fc1_w, fc1_b, fc2_w, fc2_b, (float*)d_out);
}

// Round 7
// 695.431 us; speedup vs baseline: 1.1416x; 1.0130x over previous
//
#include <hip/hip_runtime.h>
#include <hip/hip_bf16.h>
#include <hip/hip_fp8.h>
#include <cstdint>
#include <cstddef>

#define INVS 0.99999500003749968f  // 1/sqrt(1+1e-5)
#define G_GRAPHS 256

using bf16 = __hip_bfloat16;
using short8 = __attribute__((ext_vector_type(8))) short;
using floatx4 = __attribute__((ext_vector_type(4))) float;

// ---------- helpers ----------
__device__ __forceinline__ unsigned short f2bf(float v) {
    union { float f; unsigned u; } x; x.f = v;
    unsigned r = x.u + 0x7fffu + ((x.u >> 16) & 1u);
    return (unsigned short)(r >> 16);
}
__device__ __forceinline__ float bfu(unsigned short u) { return __uint_as_float((unsigned)u << 16); }
__device__ __forceinline__ float bfu_lo(unsigned v) { return __uint_as_float(v << 16); }
__device__ __forceinline__ float bfu_hi(unsigned v) { return __uint_as_float(v & 0xffff0000u); }
__device__ __forceinline__ float fp82f(unsigned char b) {
    __hip_fp8_e4m3 q; q.__x = b; return (float)q;
}
// pack 2 f32 -> 2 bf16 in one u32 (lo = a, hi = b), HW RNE (matches f2bf for finite values)
__device__ __forceinline__ unsigned pk_bf16(float a, float b) {
    unsigned r;
    asm("v_cvt_pk_bf16_f32 %0, %1, %2" : "=v"(r) : "v"(a), "v"(b));
    return r;
}
// pack 4 f32 -> 4 fp8 bytes [a,b,c,d]
__device__ __forceinline__ unsigned pk_fp8x4(float a, float b, float c, float d) {
#if __has_builtin(__builtin_amdgcn_cvt_pk_fp8_f32)
    int u = __builtin_amdgcn_cvt_pk_fp8_f32(a, b, 0, false);
    u = __builtin_amdgcn_cvt_pk_fp8_f32(c, d, u, true);
    return (unsigned)u;
#else
    __hip_fp8_e4m3 qa(a), qb(b), qc(c), qd(d);
    return (unsigned)qa.__x | ((unsigned)qb.__x << 8) | ((unsigned)qc.__x << 16) | ((unsigned)qd.__x << 24);
#endif
}

// ---------- CSR build ----------
__global__ void degi_k(const int* __restrict__ dst, int* __restrict__ degi, int E) {
    int gid = blockIdx.x * 256 + threadIdx.x;
    if (gid < E) atomicAdd(&degi[dst[gid]], 1);
}

__global__ __launch_bounds__(1024) void scan_blk_k(const int* __restrict__ degi,
                                                   int* __restrict__ off,
                                                   int* __restrict__ bsum, int N) {
    __shared__ int buf[1024];
    int t = threadIdx.x;
    int base = blockIdx.x * 2048;
    int i0 = base + 2 * t, i1 = base + 2 * t + 1;
    int v0 = (i0 < N) ? (degi[i0] + 1) : 0;
    int v1 = (i1 < N) ? (degi[i1] + 1) : 0;
    int s = v0 + v1;
    buf[t] = s;
    __syncthreads();
    for (int ofs = 1; ofs < 1024; ofs <<= 1) {
        int add = (t >= ofs) ? buf[t - ofs] : 0;
        __syncthreads();
        buf[t] += add;
        __syncthreads();
    }
    int excl = buf[t] - s;
    if (i0 < N) off[i0] = excl;
    if (i1 < N) off[i1] = excl + v0;
    if (t == 1023) bsum[blockIdx.x] = buf[1023];
}

__global__ void scan_top_k(const int* __restrict__ bsum, int* __restrict__ boff,
                           int* __restrict__ off, int NBLK, int N) {
    if (threadIdx.x == 0 && blockIdx.x == 0) {
        int run = 0;
        for (int i = 0; i < NBLK; ++i) { boff[i] = run; run += bsum[i]; }
        off[N] = run;
    }
}

__global__ void scan_add_k(int* __restrict__ off, const int* __restrict__ boff, int N) {
    int gid = blockIdx.x * 256 + threadIdx.x;
    if (gid < N) off[gid] += boff[gid >> 11];
}

__global__ void fill_csr_k(const int* __restrict__ src, const int* __restrict__ dst,
                           const int* __restrict__ off, int* __restrict__ fillc,
                           int* __restrict__ csr_src, int* __restrict__ csr_dst,
                           int* __restrict__ csr_eid, int E, int N) {
    int gid = blockIdx.x * 256 + threadIdx.x;
    if (gid < E) {
        int d = dst[gid];
        int slot = off[d] + atomicAdd(&fillc[d], 1);
        csr_src[slot] = src[gid];
        csr_dst[slot] = d;
        csr_eid[slot] = gid;
    }
    if (gid < N) {
        int slot = off[gid + 1] - 1;   // reserved last slot = self-loop
        csr_src[slot] = gid;
        csr_dst[slot] = gid;
        csr_eid[slot] = E + gid;       // >= E marks self-loop
    }
}

// ---------- weight prep for MFMA edge MLP1 (factored) ----------
__global__ void conv_weights1_k(const float* __restrict__ w1, const float* __restrict__ w2,
                                short* __restrict__ w1p, short* __restrict__ w1c,
                                short* __restrict__ w2s) {
    int gid = blockIdx.x * 256 + threadIdx.x;
    if (gid < 1024) {
        int f = gid >> 6, lane = gid & 63;
        int kk = f >> 3, tt = f & 7;
        int n = tt * 16 + (lane & 15);
        int k0 = kk * 32 + (lane >> 4) * 8;
        short8 v;
        for (int j = 0; j < 8; ++j) {
            int k = k0 + j;
            float x = (n < 64) ? w1[k * 64 + n] : w1[(64 + k) * 64 + (n - 64)];
            v[j] = (short)f2bf(x);
        }
        *(short8*)(w1p + (long long)gid * 8) = v;
    } else if (gid < 1280) {
        int g2 = gid - 1024;
        int tt = g2 >> 6, lane = g2 & 63;
        int n = tt * 16 + (lane & 15);
        int k0 = (lane >> 4) * 8;
        short8 v;
        for (int j = 0; j < 8; ++j) {
            int k = k0 + j;
            v[j] = (k < 16) ? (short)f2bf(w1[(128 + k) * 64 + n]) : (short)0;
        }
        *(short8*)(w1c + (long long)g2 * 8) = v;
    } else if (gid < 2304) {
        int g2 = gid - 1280;
        int f = g2 >> 6, lane = g2 & 63;
        int kk = f >> 3, tt = f & 7;
        int n = tt * 16 + (lane & 15);
        int k0 = kk * 32 + (lane >> 4) * 8;
        short8 v;
        for (int j = 0; j < 8; ++j) v[j] = (short)f2bf(w2[(k0 + j) * 128 + n]);
        *(short8*)(w2s + (long long)g2 * 8) = v;
    }
}

// ---------- ew prep: ew[128][256] -> frags 4 kk x 16 tt ----------
__global__ void conv_ew_k(const float* __restrict__ ew, short* __restrict__ ews) {
    int gid = blockIdx.x * 256 + threadIdx.x;
    if (gid >= 4096) return;
    int f = gid >> 6, lane = gid & 63;
    int kk = f >> 4, tt = f & 15;
    int n = tt * 16 + (lane & 15);
    int k0 = kk * 32 + (lane >> 4) * 8;
    short8 v;
    for (int j = 0; j < 8; ++j) v[j] = (short)f2bf(ew[(k0 + j) * 256 + n]);
    *(short8*)(ews + (long long)gid * 8) = v;
}

// ---------- node-linear weight prep: [wl|wr] (K x 512) -> frags ----------
template <int K>
__global__ void conv_nodew_k(const float* __restrict__ wl, const float* __restrict__ wr,
                             short* __restrict__ out) {
    int gid = blockIdx.x * 256 + threadIdx.x;
    if (gid >= (K / 32) * 32 * 64) return;
    int f = gid >> 6, lane = gid & 63;
    int kk = f >> 5, tt = f & 31;
    int n = tt * 16 + (lane & 15);
    int k0 = kk * 32 + (lane >> 4) * 8;
    short8 v;
    for (int j = 0; j < 8; ++j) {
        int k = k0 + j;
        float x = (n < 256) ? wl[k * 256 + n] : wr[k * 256 + (n - 256)];
        v[j] = (short)f2bf(x);
    }
    *(short8*)(out + (long long)gid * 8) = v;
}

// ---------- pre2 weight prep ----------
__global__ void conv_pre2w_k(const float* __restrict__ w1, short* __restrict__ out) {
    int gid = blockIdx.x * 256 + threadIdx.x;
    if (gid >= 8 * 16 * 64) return;
    int f = gid >> 6, lane = gid & 63;
    int kk = f >> 4, tt = f & 15;
    int n = tt * 16 + (lane & 15);
    int k0 = kk * 32 + (lane >> 4) * 8;
    short8 v;
    for (int j = 0; j < 8; ++j) {
        int k = k0 + j;
        float x = (n < 128) ? w1[k * 128 + n] : w1[(256 + k) * 128 + (n - 128)];
        v[j] = (short)f2bf(x);
    }
    *(short8*)(out + (long long)gid * 8) = v;
}

// ---------- pre1: pre1[n] = [ x@W1a | x@W1b + b1 ]  (N x 128 bf16) ----------
__global__ __launch_bounds__(256) void pre1_mfma_k(
    const float* __restrict__ x, const short* __restrict__ w1p,
    const float* __restrict__ b1, bf16* __restrict__ pre1, int N) {
    __shared__ short At[16][72];
    __shared__ short Ot[16][136];
    int t = threadIdx.x;
    long long n0 = (long long)blockIdx.x * 16;
    {
        int r = t >> 4, c = t & 15;
        long long n = n0 + r;
        float4 v = {0.f, 0.f, 0.f, 0.f};
        if (n < N) v = *(const float4*)(x + n * 64 + c * 4);
        ushort4 pk;
        pk.x = f2bf(v.x); pk.y = f2bf(v.y); pk.z = f2bf(v.z); pk.w = f2bf(v.w);
        *(ushort4*)&At[r][c * 4] = pk;
    }
    __syncthreads();
    int w = t >> 6, lane = t & 63;
    int nq = w * 2;
    int lr = lane & 15, lq = lane >> 4;
    floatx4 acc[2];
    for (int i = 0; i < 2; ++i) acc[i] = (floatx4){0.f, 0.f, 0.f, 0.f};
    for (int kk = 0; kk < 2; ++kk) {
        short8 a = *(const short8*)&At[lr][kk * 32 + lq * 8];
        for (int tt = 0; tt < 2; ++tt) {
            short8 b = *(const short8*)(w1p + ((long long)((kk * 8 + nq + tt) * 64 + lane)) * 8);
            acc[tt] = __builtin_amdgcn_mfma_f32_16x16x32_bf16(a, b, acc[tt], 0, 0, 0);
        }
    }
    for (int tt = 0; tt < 2; ++tt) {
        int col = (nq + tt) * 16 + lr;
        float bv = (col >= 64) ? b1[col - 64] : 0.f;
        for (int r = 0; r < 4; ++r)
            Ot[lq * 4 + r][col] = (short)f2bf(acc[tt][r] + bv);
    }
    __syncthreads();
    {
        int r = t >> 4, c = t & 15;
        long long n = n0 + r;
        if (n < N)
            *(short8*)(void*)(pre1 + n * 128 + c * 8) = *(const short8*)&Ot[r][c * 8];
    }
}

// ---------- Edge MLP 1 via MFMA (swapped operands: A=weights, B=data) ----------
// acc = pre1_s[src]+pre1_d[dst](+b1) ; + ea@W1c ; relu ; @W2 ; @ews -> fp8 ee8.
// C-layout is channel-major per lane -> float4 acc-init, pk_bf16/pk_fp8 packed stores.
__global__ __launch_bounds__(256) void edge_mlp1_mfma_k(
    const bf16* __restrict__ pre1, const float* __restrict__ ea,
    const int* __restrict__ csr_src, const int* __restrict__ csr_dst,
    const int* __restrict__ csr_eid,
    const short* __restrict__ w1c,
    const short* __restrict__ w2s, const float* __restrict__ b2,
    const short* __restrict__ ews,
    unsigned char* __restrict__ ee8, int NT, int E) {
    __shared__ float Ps[32][76];         // PsA (64 chans); dead after A1 -> Et alias (32*272 B)
    __shared__ short Ae[32][40];         // ea tile: 16 valid K + 16 zero-pad
    __shared__ short Ht[32][72];         // hidden (64 chans)
    __shared__ short A2[32][136];        // ea2 tile (128 chans)
    __shared__ int sdv[32][3];
    unsigned char* Et = (unsigned char*)&Ps[0][0];
    int t = threadIdx.x;
    long long s0 = (long long)blockIdx.x * 32;
    if (t < 96) {
        int r = t & 31, which = t >> 5;
        long long s = s0 + r;
        int v = (which == 2) ? E : 0;
        if (s < NT) v = (which == 0) ? csr_src[s] : (which == 1 ? csr_dst[s] : csr_eid[s]);
        sdv[r][which] = v;
    }
    __syncthreads();
    {   // PsA init: pre1[src][0:64] + pre1[dst][64:128]
        int r = t >> 3, c = t & 7;
        long long s = s0 + r;
        bool ok = (s < NT) && (sdv[r][2] < E);
        float p[8];
        if (ok) {
            short8 vs = *(const short8*)(const void*)(pre1 + (long long)sdv[r][0] * 128 + c * 8);
            short8 vd = *(const short8*)(const void*)(pre1 + (long long)sdv[r][1] * 128 + 64 + c * 8);
            for (int j = 0; j < 8; ++j)
                p[j] = bfu((unsigned short)vs[j]) + bfu((unsigned short)vd[j]);
        } else {
            for (int j = 0; j < 8; ++j) p[j] = 0.f;
        }
        for (int j = 0; j < 8; ++j) Ps[r][c * 8 + j] = p[j];
    }
    if (t < 128) {   // ea gather: 16 floats/row
        int r = t >> 2, c = t & 3;
        long long s = s0 + r;
        int eid = sdv[r][2];
        float4 v = {0.f, 0.f, 0.f, 0.f};
        if (s < NT && eid < E) v = *(const float4*)(ea + (long long)eid * 16 + c * 4);
        ushort4 pk;
        pk.x = f2bf(v.x); pk.y = f2bf(v.y); pk.z = f2bf(v.z); pk.w = f2bf(v.w);
        *(ushort4*)&Ae[r][c * 4] = pk;
    } else {         // zero-pad K 16..31
        int i = t - 128;
        int r = i >> 2, c = i & 3;
        *(ushort4*)&Ae[r][16 + c * 4] = (ushort4){0, 0, 0, 0};
    }
    __syncthreads();

    int w = t >> 6, lane = t & 63;
    int sl = (w & 1) * 16 + (lane & 15);   // this lane's slot
    int lq = lane >> 4;

    // phase 1: h1 = relu(PsA + ea@W1c)  (64 chans, 4 m-tiles; 2 per wave)
    {
        int mb = (w >> 1) * 2;
        floatx4 acc[2];
        #pragma unroll
        for (int tt = 0; tt < 2; ++tt)
            acc[tt] = *(const floatx4*)&Ps[sl][(mb + tt) * 16 + lq * 4];
        short8 bfr = *(const short8*)&Ae[sl][lq * 8];
        #pragma unroll
        for (int tt = 0; tt < 2; ++tt) {
            short8 a = *(const short8*)(w1c + ((long long)((mb + tt) * 64 + lane)) * 8);
            acc[tt] = __builtin_amdgcn_mfma_f32_16x16x32_bf16(a, bfr, acc[tt], 0, 0, 0);
        }
        #pragma unroll
        for (int tt = 0; tt < 2; ++tt) {
            int ch0 = (mb + tt) * 16 + lq * 4;
            uint2 o;
            o.x = pk_bf16(fmaxf(acc[tt][0], 0.f), fmaxf(acc[tt][1], 0.f));
            o.y = pk_bf16(fmaxf(acc[tt][2], 0.f), fmaxf(acc[tt][3], 0.f));
            *(uint2*)&Ht[sl][ch0] = o;
        }
    }
    __syncthreads();

    // phase 2: ea2 = h1 @ W2 + b2  (128 chans, 8 m-tiles; 4 per wave)
    {
        int mb = (w >> 1) * 4;
        floatx4 acc2[4];
        #pragma unroll
        for (int i = 0; i < 4; ++i) acc2[i] = (floatx4){0.f, 0.f, 0.f, 0.f};
        #pragma unroll
        for (int kk = 0; kk < 2; ++kk) {
            short8 bfr = *(const short8*)&Ht[sl][kk * 32 + lq * 8];
            #pragma unroll
            for (int tt = 0; tt < 4; ++tt) {
                short8 a = *(const short8*)(w2s + ((long long)((kk * 8 + mb + tt) * 64 + lane)) * 8);
                acc2[tt] = __builtin_amdgcn_mfma_f32_16x16x32_bf16(a, bfr, acc2[tt], 0, 0, 0);
            }
        }
        #pragma unroll
        for (int tt = 0; tt < 4; ++tt) {
            int ch0 = (mb + tt) * 16 + lq * 4;
            float4 bv = *(const float4*)(b2 + ch0);
            uint2 o;
            o.x = pk_bf16(acc2[tt][0] + bv.x, acc2[tt][1] + bv.y);
            o.y = pk_bf16(acc2[tt][2] + bv.z, acc2[tt][3] + bv.w);
            *(uint2*)&A2[sl][ch0] = o;
        }
    }
    __syncthreads();

    // phase 3: ee = ea2 @ ews (K=128 -> 256 chans, 16 m-tiles; 8 per wave), fp8 pack into Et
    {
        int mb = (w >> 1) * 8;
        floatx4 acc3[8];
        #pragma unroll
        for (int i = 0; i < 8; ++i) acc3[i] = (floatx4){0.f, 0.f, 0.f, 0.f};
        #pragma unroll
        for (int kk = 0; kk < 4; ++kk) {
            short8 bfr = *(const short8*)&A2[sl][kk * 32 + lq * 8];
            #pragma unroll
            for (int tt = 0; tt < 8; ++tt) {
                short8 a = *(const short8*)(ews + ((long long)((kk * 16 + mb + tt) * 64 + lane)) * 8);
                acc3[tt] = __builtin_amdgcn_mfma_f32_16x16x32_bf16(a, bfr, acc3[tt], 0, 0, 0);
            }
        }
        #pragma unroll
        for (int tt = 0; tt < 8; ++tt) {
            int ch0 = (mb + tt) * 16 + lq * 4;
            unsigned u = pk_fp8x4(acc3[tt][0], acc3[tt][1], acc3[tt][2], acc3[tt][3]);
            *(unsigned*)(Et + sl * 272 + ch0) = u;
        }
    }
    __syncthreads();
    for (int i = t; i < 512; i += 256) {
        int r = i >> 4, c = i & 15;
        long long s = s0 + r;
        if (s < NT)
            *(uint4*)(ee8 + s * 256 + c * 16) = *(const uint4*)(Et + r * 272 + c * 16);
    }
}

// ---------- node linear via MFMA (swapped operands): [N x K] @ [K x 512] + bias ----------
// NOTE: x may alias xr (x1bn overlay) — per-block reads complete before same-row writes.
template <int K, typename T>
__global__ __launch_bounds__(256) void node_linear_mfma_k(
    const T* x, const short* __restrict__ ws,
    const float* __restrict__ bl, const float* __restrict__ br,
    bf16* __restrict__ xl, bf16* xr, int N) {
    __shared__ short At[16][K + 8];
    __shared__ short Ot[16][520];
    int t = threadIdx.x;
    long long n0 = (long long)blockIdx.x * 16;
    if (sizeof(T) == 4) {
        for (int i = t; i < 16 * (K / 4); i += 256) {
            int r = i / (K / 4), c = i % (K / 4);
            long long n = n0 + r;
            float4 v = {0.f, 0.f, 0.f, 0.f};
            if (n < N) v = *(const float4*)((const float*)x + n * K + c * 4);
            ushort4 pk;
            pk.x = f2bf(v.x); pk.y = f2bf(v.y); pk.z = f2bf(v.z); pk.w = f2bf(v.w);
            *(ushort4*)&At[r][c * 4] = pk;
        }
    } else {
        for (int i = t; i < 16 * (K / 8); i += 256) {
            int r = i / (K / 8), c = i % (K / 8);
            long long n = n0 + r;
            short8 v = {0, 0, 0, 0, 0, 0, 0, 0};
            if (n < N) v = *(const short8*)(const void*)((const bf16*)x + n * K + c * 8);
            *(short8*)&At[r][c * 8] = v;
        }
    }
    __syncthreads();

    int w = t >> 6, lane = t & 63;
    int nr = lane & 15, lq = lane >> 4;

    floatx4 acc[8];
    #pragma unroll
    for (int i = 0; i < 8; ++i) acc[i] = (floatx4){0.f, 0.f, 0.f, 0.f};
    for (int kk = 0; kk < K / 32; ++kk) {
        short8 bfr = *(const short8*)&At[nr][kk * 32 + lq * 8];
        #pragma unroll
        for (int tt = 0; tt < 8; ++tt) {
            short8 a = *(const short8*)(ws + ((long long)((kk * 32 + w * 8 + tt) * 64 + lane)) * 8);
            acc[tt] = __builtin_amdgcn_mfma_f32_16x16x32_bf16(a, bfr, acc[tt], 0, 0, 0);
        }
    }
    #pragma unroll
    for (int tt = 0; tt < 8; ++tt) {
        int ch0 = (w * 8 + tt) * 16 + lq * 4;
        const float* bp = (ch0 < 256) ? (bl + ch0) : (br + (ch0 - 256));
        float4 bv = *(const float4*)bp;
        uint2 o;
        o.x = pk_bf16(acc[tt][0] + bv.x, acc[tt][1] + bv.y);
        o.y = pk_bf16(acc[tt][2] + bv.z, acc[tt][3] + bv.w);
        *(uint2*)&Ot[nr][ch0] = o;
    }
    __syncthreads();
    for (int i = t; i < 1024; i += 256) {
        int r = i >> 6, c = i & 63;
        long long n = n0 + r;
        if (n < N) {
            short8 v = *(const short8*)&Ot[r][c * 8];
            if (c < 32) *(short8*)(void*)(xl + n * 256 + c * 8) = v;
            else        *(short8*)(void*)(xr + n * 256 + (c - 32) * 8) = v;
        }
    }
}

// ---------- pre2 (swapped operands): xp = x1bn @ M[256x256] + b1x -> xl ----------
__global__ __launch_bounds__(256) void pre_mfma_k(
    const bf16* __restrict__ x, const short* __restrict__ ws,
    const float* __restrict__ bx, bf16* __restrict__ out, int N) {
    __shared__ short At[16][264];
    __shared__ short Ot[16][264];
    int t = threadIdx.x;
    long long n0 = (long long)blockIdx.x * 16;
    for (int i = t; i < 512; i += 256) {
        int r = i >> 5, c = i & 31;
        long long n = n0 + r;
        short8 v = {0, 0, 0, 0, 0, 0, 0, 0};
        if (n < N) v = *(const short8*)(const void*)(x + n * 256 + c * 8);
        *(short8*)&At[r][c * 8] = v;
    }
    __syncthreads();

    int w = t >> 6, lane = t & 63;
    int nr = lane & 15, lq = lane >> 4;

    floatx4 acc[4];
    #pragma unroll
    for (int i = 0; i < 4; ++i) acc[i] = (floatx4){0.f, 0.f, 0.f, 0.f};
    for (int kk = 0; kk < 8; ++kk) {
        short8 bfr = *(const short8*)&At[nr][kk * 32 + lq * 8];
        #pragma unroll
        for (int tt = 0; tt < 4; ++tt) {
            short8 a = *(const short8*)(ws + ((long long)((kk * 16 + w * 4 + tt) * 64 + lane)) * 8);
            acc[tt] = __builtin_amdgcn_mfma_f32_16x16x32_bf16(a, bfr, acc[tt], 0, 0, 0);
        }
    }
    #pragma unroll
    for (int tt = 0; tt < 4; ++tt) {
        int ch0 = (w * 4 + tt) * 16 + lq * 4;
        float4 bv = *(const float4*)(bx + ch0);
        uint2 o;
        o.x = pk_bf16(acc[tt][0] + bv.x, acc[tt][1] + bv.y);
        o.y = pk_bf16(acc[tt][2] + bv.z, acc[tt][3] + bv.w);
        *(uint2*)&Ot[nr][ch0] = o;
    }
    __syncthreads();
    for (int i = t; i < 512; i += 256) {
        int r = i >> 5, c = i & 31;
        long long n = n0 + r;
        if (n < N)
            *(short8*)(void*)(out + n * 256 + c * 8) = *(const short8*)&Ot[r][c * 8];
    }
}

// ---------- Fused GATv2 attention + aggregation + finalize ----------
// Depth-2 data prefetch (xl/ee8) + depth-3 index prefetch (csr_src); ee8 reads
// are non-temporal (each row consumed exactly once, keep L2 for xl re-use).
template <bool L1>
__global__ __launch_bounds__(256) void gat_fused_k(
    const unsigned char* __restrict__ ee8, const bf16* __restrict__ xl, const bf16* xr,
    const int* __restrict__ off, const int* __restrict__ csr_src,
    const float* __restrict__ att, const float* __restrict__ bias,
    const float* __restrict__ bng, const float* __restrict__ bnb,
    const int* __restrict__ batch,
    bf16* x1bn, float* __restrict__ pooled, int N) {
    __shared__ float ps[4][260];
    __shared__ int bid[4];
    int t = threadIdx.x;
    int w = t >> 6, lane = t & 63;
    int n = blockIdx.x * 4 + w;
    bool valid = n < N;
    int c0 = lane * 4;
    float o0 = 0.f, o1 = 0.f, o2 = 0.f, o3 = 0.f;
    if (valid) {
        ushort4 xrp = *(const ushort4*)(const void*)(xr + (long long)n * 256 + c0);
        ushort4 xop = *(const ushort4*)(const void*)(xl + (long long)n * 256 + c0);
        float xr0 = bfu(xrp.x), xr1 = bfu(xrp.y), xr2 = bfu(xrp.z), xr3 = bfu(xrp.w);
        float4 atv = *(const float4*)(att + c0);
        float a0 = 0.f, a1 = 0.f, a2 = 0.f, a3 = 0.f, dacc = 0.f;
        float es0 = 0.f, es1 = 0.f, es2 = 0.f, es3 = 0.f;
        int beg = off[n], end1 = off[n + 1] - 1;   // [beg, end1) = real edges; end1 = self-loop
        // prefetch pipeline: data depth 2, index depth 3
        ushort4 xlp0, xlp1 = {0, 0, 0, 0};
        unsigned ep0 = 0, ep1 = 0;
        {
            int sid = csr_src[beg];   // valid even for deg-0 (self-loop slot)
            xlp0 = *(const ushort4*)(const void*)(xl + (long long)sid * 256 + c0);
            ep0 = __builtin_nontemporal_load((const unsigned*)(ee8 + (long long)beg * 256 + c0));
        }
        if (beg + 1 < end1) {
            int sid = csr_src[beg + 1];
            xlp1 = *(const ushort4*)(const void*)(xl + (long long)sid * 256 + c0);
            ep1 = __builtin_nontemporal_load((const unsigned*)(ee8 + (long long)(beg + 1) * 256 + c0));
        }
        int sid2 = (beg + 2 < end1) ? csr_src[beg + 2] : 0;
        for (int i = beg; i < end1; ++i) {
            ushort4 cx = xlp0;
            unsigned ce = ep0;
            xlp0 = xlp1; ep0 = ep1;
            if (i + 2 < end1) {
                xlp1 = *(const ushort4*)(const void*)(xl + (long long)sid2 * 256 + c0);
                ep1 = __builtin_nontemporal_load((const unsigned*)(ee8 + (long long)(i + 2) * 256 + c0));
                sid2 = (i + 3 < end1) ? csr_src[i + 3] : 0;
            }
            float x0 = bfu(cx.x), x1 = bfu(cx.y), x2 = bfu(cx.z), x3 = bfu(cx.w);
            float e0 = fp82f(ce & 0xff);
            float e1 = fp82f((ce >> 8) & 0xff);
            float e2 = fp82f((ce >> 16) & 0xff);
            float e3 = fp82f(ce >> 24);
            es0 += e0; es1 += e1; es2 += e2; es3 += e3;
            float m0 = x0 + xr0 + e0;
            float m1 = x1 + xr1 + e1;
            float m2 = x2 + xr2 + e2;
            float m3 = x3 + xr3 + e3;
            m0 = m0 > 0.f ? m0 : 0.2f * m0;
            m1 = m1 > 0.f ? m1 : 0.2f * m1;
            m2 = m2 > 0.f ? m2 : 0.2f * m2;
            m3 = m3 > 0.f ? m3 : 0.2f * m3;
            float p = atv.x * m0 + atv.y * m1 + atv.z * m2 + atv.w * m3;
            p += __shfl_xor(p, 1, 64);
            p += __shfl_xor(p, 2, 64);
            p += __shfl_xor(p, 4, 64);
            p += __shfl_xor(p, 8, 64);
            float ex = expf(p);
            a0 += ex * x0; a1 += ex * x1; a2 += ex * x2; a3 += ex * x3;
            dacc += ex;
        }
        // self-loop term: edge feature = mean of incoming ee
        {
            float rdv = 1.f / fmaxf((float)(end1 - beg), 1.f);
            float x0 = bfu(xop.x), x1 = bfu(xop.y), x2 = bfu(xop.z), x3 = bfu(xop.w);
            float m0 = x0 + xr0 + es0 * rdv;
            float m1 = x1 + xr1 + es1 * rdv;
            float m2 = x2 + xr2 + es2 * rdv;
            float m3 = x3 + xr3 + es3 * rdv;
            m0 = m0 > 0.f ? m0 : 0.2f * m0;
            m1 = m1 > 0.f ? m1 : 0.2f * m1;
            m2 = m2 > 0.f ? m2 : 0.2f * m2;
            m3 = m3 > 0.f ? m3 : 0.2f * m3;
            float p = atv.x * m0 + atv.y * m1 + atv.z * m2 + atv.w * m3;
            p += __shfl_xor(p, 1, 64);
            p += __shfl_xor(p, 2, 64);
            p += __shfl_xor(p, 4, 64);
            p += __shfl_xor(p, 8, 64);
            float ex = expf(p);
            a0 += ex * x0; a1 += ex * x1; a2 += ex * x2; a3 += ex * x3;
            dacc += ex;
        }
        float inv = 1.f / dacc;
        o0 = fmaxf(a0 * inv + bias[c0],     0.f);
        o1 = fmaxf(a1 * inv + bias[c0 + 1], 0.f);
        o2 = fmaxf(a2 * inv + bias[c0 + 2], 0.f);
        o3 = fmaxf(a3 * inv + bias[c0 + 3], 0.f);
        if (L1) {
            ushort4 o;
            o.x = f2bf(bng[c0]     * (o0 * INVS) + bnb[c0]);
            o.y = f2bf(bng[c0 + 1] * (o1 * INVS) + bnb[c0 + 1]);
            o.z = f2bf(bng[c0 + 2] * (o2 * INVS) + bnb[c0 + 2]);
            o.w = f2bf(bng[c0 + 3] * (o3 * INVS) + bnb[c0 + 3]);
            *(ushort4*)(void*)(x1bn + (long long)n * 256 + c0) = o;
        }
    }
    if (lane == 0) bid[w] = valid ? batch[n] : -1;
    ps[w][c0]     = o0;
    ps[w][c0 + 1] = o1;
    ps[w][c0 + 2] = o2;
    ps[w][c0 + 3] = o3;
    __syncthreads();
    int b0 = bid[0];
    bool same = (b0 >= 0)
             && (bid[1] < 0 || bid[1] == b0)
             && (bid[2] < 0 || bid[2] == b0)
             && (bid[3] < 0 || bid[3] == b0);
    if (same) {
        float s = ps[0][t] + ps[1][t] + ps[2][t] + ps[3][t];
        atomicAdd(&pooled[(long long)b0 * 256 + t], s);
    } else if (valid) {
        long long pb = (long long)bid[w] * 256 + c0;
        atomicAdd(&pooled[pb],     o0);
        atomicAdd(&pooled[pb + 1], o1);
        atomicAdd(&pooled[pb + 2], o2);
        atomicAdd(&pooled[pb + 3], o3);
    }
}

// ---------- global MLP layer1 ----------
__global__ void global_mlp1_k(const float* __restrict__ pooled,
                              const float* __restrict__ w1, const float* __restrict__ b1,
                              const float* __restrict__ w2, const float* __restrict__ b2,
                              const float* __restrict__ bng, const float* __restrict__ bnb,
                              float* __restrict__ u1bn) {
    __shared__ float pr[256];
    __shared__ float h[256];
    int t = threadIdx.x, g = blockIdx.x;
    pr[t] = pooled[g * 256 + t];
    __syncthreads();
    float acc = b1[t];
    for (int k = 0; k < 256; ++k) acc += pr[k] * w1[(256 + k) * 256 + t];
    h[t] = fmaxf(acc, 0.f);
    __syncthreads();
    float a2 = b2[t];
    for (int k = 0; k < 256; ++k) a2 += h[k] * w2[k * 256 + t];
    u1bn[g * 256 + t] = bng[t] * (a2 * INVS) + bnb[t];
}

// ---------- weight prep for MFMA edge MLP2 (+ b1x for pre path) ----------
__global__ void conv_weights_k(const float* __restrict__ w1, const float* __restrict__ w2,
                               const float* __restrict__ b1,
                               const float* __restrict__ bg, const float* __restrict__ bb,
                               short* __restrict__ w1s, short* __restrict__ w2s,
                               float* __restrict__ b1x) {
    int gid = blockIdx.x * 256 + threadIdx.x;
    if (gid < 10240) {
        int f = gid >> 6, lane = gid & 63;
        int kk = f >> 3, tt = f & 7;
        int n = tt * 16 + (lane & 15);
        int k0 = kk * 32 + (lane >> 4) * 8;
        short8 v;
        for (int j = 0; j < 8; ++j) {
            int k = k0 + j;
            float x = w1[k * 128 + n];
            if (k >= 512) x *= bg[k - 512] * INVS;
            v[j] = (short)f2bf(x);
        }
        *(short8*)(w1s + (long long)gid * 8) = v;
    } else if (gid < 12288) {
        int g2 = gid - 10240;
        int f = g2 >> 6, lane = g2 & 63;
        int kk = f >> 3, tt = f & 7;
        int n = tt * 16 + (lane & 15);
        int k0 = kk * 32 + (lane >> 4) * 8;
        short8 v;
        for (int j = 0; j < 8; ++j) v[j] = (short)f2bf(w2[(k0 + j) * 128 + n]);
        *(short8*)(w2s + (long long)g2 * 8) = v;
    } else if (gid < 12544) {
        int j = gid - 12288;
        b1x[j] = 0.f;
    } else if (gid < 12672) {
        int j = gid - 12544;
        float acc = b1[j];
        for (int c = 0; c < 128; ++c) acc += bb[c] * w1[(512 + c) * 128 + j];
        b1x[128 + j] = acc;
    }
}

// ---------- Edge MLP 2 via MFMA (swapped operands), fused with ee-GEMM; ea2 recomputed ----------
// LDS diet: Ps tiles stored as packed bf16 (downstream is fp8-quantized; bf16 rounding of the
// pre-sums is ~64x below the fp8 noise floor). Aliasing:
//   Zt: PsA(cols 0..63) + Ae(cols 96..135)  [stage..A1]  ->  At (ea2 tile)  [A2..]
//   Xt: PsB bf16 [A2-overlap..B1]           ->  Et (fp8 tile, 272 B rows)  [B3..]
// Total LDS 26.5 KB -> 6 blocks/CU (was 38.4 KB -> 4).
__global__ __launch_bounds__(256) void edge_mlp2_mfma_k(
    const bf16* __restrict__ xpre, const bf16* __restrict__ pre1,
    const float* __restrict__ ea,
    const int* __restrict__ csr_src, const int* __restrict__ csr_dst,
    const int* __restrict__ csr_eid,
    const short* __restrict__ w1c, const short* __restrict__ w2s1,
    const float* __restrict__ e1_b2,
    const short* __restrict__ w1s,       // uses kk 16..19 (ea rows, BN-folded)
    const short* __restrict__ w2s, const float* __restrict__ b2,
    const short* __restrict__ ews,
    unsigned char* __restrict__ ee8, int NT, int E) {
    __shared__ short Zt[32][136];
    __shared__ short Ht[32][136];
    __shared__ short Xt[32][136];
    __shared__ int sdv[32][3];
    unsigned char* Et = (unsigned char*)&Xt[0][0];   // 272 B rows
    int t = threadIdx.x;
    long long s0 = (long long)blockIdx.x * 32;
    if (t < 96) {
        int r = t & 31, which = t >> 5;
        long long s = s0 + r;
        int v = (which == 2) ? E : 0;
        if (s < NT) v = (which == 0) ? csr_src[s] : (which == 1 ? csr_dst[s] : csr_eid[s]);
        sdv[r][which] = v;
    }
    __syncthreads();
    {   // PsA init (bf16-packed): pre1[src][0:64] + pre1[dst][64:128] -> Zt cols 0..63
        int r = t >> 3, c = t & 7;
        long long s = s0 + r;
        bool ok = (s < NT) && (sdv[r][2] < E);
        uint4 o = {0, 0, 0, 0};
        if (ok) {
            short8 vs = *(const short8*)(const void*)(pre1 + (long long)sdv[r][0] * 128 + c * 8);
            short8 vd = *(const short8*)(const void*)(pre1 + (long long)sdv[r][1] * 128 + 64 + c * 8);
            float p[8];
            #pragma unroll
            for (int j = 0; j < 8; ++j)
                p[j] = bfu((unsigned short)vs[j]) + bfu((unsigned short)vd[j]);
            o.x = pk_bf16(p[0], p[1]); o.y = pk_bf16(p[2], p[3]);
            o.z = pk_bf16(p[4], p[5]); o.w = pk_bf16(p[6], p[7]);
        }
        *(uint4*)&Zt[r][c * 8] = o;
    }
    if (t < 128) {   // ea gather -> Zt cols 96..111 (+ zero-pad 112..127)
        int r = t >> 2, c = t & 3;
        long long s = s0 + r;
        int eid = sdv[r][2];
        float4 v = {0.f, 0.f, 0.f, 0.f};
        if (s < NT && eid < E) v = *(const float4*)(ea + (long long)eid * 16 + c * 4);
        ushort4 pk;
        pk.x = f2bf(v.x); pk.y = f2bf(v.y); pk.z = f2bf(v.z); pk.w = f2bf(v.w);
        *(ushort4*)&Zt[r][96 + c * 4] = pk;
    } else {
        int i = t - 128;
        int r = i >> 2, c = i & 3;
        *(ushort4*)&Zt[r][96 + 16 + c * 4] = (ushort4){0, 0, 0, 0};
    }
    __syncthreads();

    int w = t >> 6, lane = t & 63;
    int sl = (w & 1) * 16 + (lane & 15);
    int lq = lane >> 4;

    // phase A1: h1 = relu(PsA + ea@W1c)  (64 chans)
    {
        int mb = (w >> 1) * 2;
        floatx4 acc[2];
        #pragma unroll
        for (int tt = 0; tt < 2; ++tt) {
            uint2 pv = *(const uint2*)&Zt[sl][(mb + tt) * 16 + lq * 4];
            acc[tt] = (floatx4){bfu_lo(pv.x), bfu_hi(pv.x), bfu_lo(pv.y), bfu_hi(pv.y)};
        }
        short8 bfr = *(const short8*)&Zt[sl][96 + lq * 8];
        #pragma unroll
        for (int tt = 0; tt < 2; ++tt) {
            short8 a = *(const short8*)(w1c + ((long long)((mb + tt) * 64 + lane)) * 8);
            acc[tt] = __builtin_amdgcn_mfma_f32_16x16x32_bf16(a, bfr, acc[tt], 0, 0, 0);
        }
        #pragma unroll
        for (int tt = 0; tt < 2; ++tt) {
            int ch0 = (mb + tt) * 16 + lq * 4;
            uint2 o;
            o.x = pk_bf16(fmaxf(acc[tt][0], 0.f), fmaxf(acc[tt][1], 0.f));
            o.y = pk_bf16(fmaxf(acc[tt][2], 0.f), fmaxf(acc[tt][3], 0.f));
            *(uint2*)&Ht[sl][ch0] = o;
        }
    }
    __syncthreads();

    // PsB init (pre2 gathers, bf16-packed -> Xt; overlaps A2 compute)
    for (int i = t; i < 512; i += 256) {
        int r = i >> 4, c = i & 15;
        long long s = s0 + r;
        bool ok = (s < NT) && (sdv[r][2] < E);
        uint4 o = {0, 0, 0, 0};
        if (ok) {
            short8 vs = *(const short8*)(const void*)(xpre + (long long)sdv[r][0] * 256 + c * 8);
            short8 vd = *(const short8*)(const void*)(xpre + (long long)sdv[r][1] * 256 + 128 + c * 8);
            float p[8];
            #pragma unroll
            for (int j = 0; j < 8; ++j)
                p[j] = bfu((unsigned short)vs[j]) + bfu((unsigned short)vd[j]);
            o.x = pk_bf16(p[0], p[1]); o.y = pk_bf16(p[2], p[3]);
            o.z = pk_bf16(p[4], p[5]); o.w = pk_bf16(p[6], p[7]);
        }
        *(uint4*)&Xt[r][c * 8] = o;
    }
    // phase A2: ea2 = h1@W2s1 + e1_b2 -> At (Zt, 128 chans)
    {
        int mb = (w >> 1) * 4;
        floatx4 acc2[4];
        #pragma unroll
        for (int i = 0; i < 4; ++i) acc2[i] = (floatx4){0.f, 0.f, 0.f, 0.f};
        #pragma unroll
        for (int kk = 0; kk < 2; ++kk) {
            short8 bfr = *(const short8*)&Ht[sl][kk * 32 + lq * 8];
            #pragma unroll
            for (int tt = 0; tt < 4; ++tt) {
                short8 a = *(const short8*)(w2s1 + ((long long)((kk * 8 + mb + tt) * 64 + lane)) * 8);
                acc2[tt] = __builtin_amdgcn_mfma_f32_16x16x32_bf16(a, bfr, acc2[tt], 0, 0, 0);
            }
        }
        #pragma unroll
        for (int tt = 0; tt < 4; ++tt) {
            int ch0 = (mb + tt) * 16 + lq * 4;
            float4 bv = *(const float4*)(e1_b2 + ch0);
            uint2 o;
            o.x = pk_bf16(acc2[tt][0] + bv.x, acc2[tt][1] + bv.y);
            o.y = pk_bf16(acc2[tt][2] + bv.z, acc2[tt][3] + bv.w);
            *(uint2*)&Zt[sl][ch0] = o;
        }
    }
    __syncthreads();

    // phase B1: h = relu(PsB + ea2@W1s[kk16..19])  (128 chans)
    {
        int mb = (w >> 1) * 4;
        floatx4 acc[4];
        #pragma unroll
        for (int tt = 0; tt < 4; ++tt) {
            uint2 pv = *(const uint2*)&Xt[sl][(mb + tt) * 16 + lq * 4];
            acc[tt] = (floatx4){bfu_lo(pv.x), bfu_hi(pv.x), bfu_lo(pv.y), bfu_hi(pv.y)};
        }
        #pragma unroll
        for (int kk = 0; kk < 4; ++kk) {
            short8 bfr = *(const short8*)&Zt[sl][kk * 32 + lq * 8];
            #pragma unroll
            for (int tt = 0; tt < 4; ++tt) {
                short8 a = *(const short8*)(w1s + ((long long)(((16 + kk) * 8 + mb + tt) * 64 + lane)) * 8);
                acc[tt] = __builtin_amdgcn_mfma_f32_16x16x32_bf16(a, bfr, acc[tt], 0, 0, 0);
            }
        }
        #pragma unroll
        for (int tt = 0; tt < 4; ++tt) {
            int ch0 = (mb + tt) * 16 + lq * 4;
            uint2 o;
            o.x = pk_bf16(fmaxf(acc[tt][0], 0.f), fmaxf(acc[tt][1], 0.f));
            o.y = pk_bf16(fmaxf(acc[tt][2], 0.f), fmaxf(acc[tt][3], 0.f));
            *(uint2*)&Ht[sl][ch0] = o;
        }
    }
    __syncthreads();

    // phase B2: ea2' = h @ W2 + b2 -> At (Zt, 128 chans)
    {
        int mb = (w >> 1) * 4;
        floatx4 acc2[4];
        #pragma unroll
        for (int i = 0; i < 4; ++i) acc2[i] = (floatx4){0.f, 0.f, 0.f, 0.f};
        #pragma unroll
        for (int kk = 0; kk < 4; ++kk) {
            short8 bfr = *(const short8*)&Ht[sl][kk * 32 + lq * 8];
            #pragma unroll
            for (int tt = 0; tt < 4; ++tt) {
                short8 a = *(const short8*)(w2s + ((long long)((kk * 8 + mb + tt) * 64 + lane)) * 8);
                acc2[tt] = __builtin_amdgcn_mfma_f32_16x16x32_bf16(a, bfr, acc2[tt], 0, 0, 0);
            }
        }
        #pragma unroll
        for (int tt = 0; tt < 4; ++tt) {
            int ch0 = (mb + tt) * 16 + lq * 4;
            float4 bv = *(const float4*)(b2 + ch0);
            uint2 o;
            o.x = pk_bf16(acc2[tt][0] + bv.x, acc2[tt][1] + bv.y);
            o.y = pk_bf16(acc2[tt][2] + bv.z, acc2[tt][3] + bv.w);
            *(uint2*)&Zt[sl][ch0] = o;
        }
    }
    __syncthreads();

    // phase B3: ee = ea2' @ ews (K=128 -> 256 chans), fp8 pack into Et (aliases dead Xt)
    {
        int mb = (w >> 1) * 8;
        floatx4 acc3[8];
        #pragma unroll
        for (int i = 0; i < 8; ++i) acc3[i] = (floatx4){0.f, 0.f, 0.f, 0.f};
        #pragma unroll
        for (int kk = 0; kk < 4; ++kk) {
            short8 bfr = *(const short8*)&Zt[sl][kk * 32 + lq * 8];
            #pragma unroll
            for (int tt = 0; tt < 8; ++tt) {
                short8 a = *(const short8*)(ews + ((long long)((kk * 16 + mb + tt) * 64 + lane)) * 8);
                acc3[tt] = __builtin_amdgcn_mfma_f32_16x16x32_bf16(a, bfr, acc3[tt], 0, 0, 0);
            }
        }
        #pragma unroll
        for (int tt = 0; tt < 8; ++tt) {
            int ch0 = (mb + tt) * 16 + lq * 4;
            unsigned u = pk_fp8x4(acc3[tt][0], acc3[tt][1], acc3[tt][2], acc3[tt][3]);
            *(unsigned*)(Et + sl * 272 + ch0) = u;
        }
    }
    __syncthreads();
    for (int i = t; i < 512; i += 256) {
        int r = i >> 4, c = i & 15;
        long long s = s0 + r;
        if (s < NT && sdv[r][2] < E)
            *(uint4*)(ee8 + s * 256 + c * 16) = *(const uint4*)(Et + r * 272 + c * 16);
    }
}

// ---------- final global MLP + head ----------
__global__ void final_mlp_k(const float* __restrict__ u1bn, const float* __restrict__ pooled,
                            const float* __restrict__ w1, const float* __restrict__ b1,
                            const float* __restrict__ w2, const float* __restrict__ b2,
                            const float* __restrict__ f1w, const float* __restrict__ f1b,
                            const float* __restrict__ f2w, const float* __restrict__ f2b,
                            float* __restrict__ out) {
    __shared__ float ub[256], pb[256], h[256], u2[256];
    int t = threadIdx.x, g = blockIdx.x;
    ub[t] = u1bn[g * 256 + t];
    pb[t] = pooled[g * 256 + t];
    __syncthreads();
    float acc = b1[t];
    for (int k = 0; k < 256; ++k)
        acc += ub[k] * w1[k * 256 + t] + pb[k] * w1[(256 + k) * 256 + t];
    h[t] = fmaxf(acc, 0.f);
    __syncthreads();
    float a2 = b2[t];
    for (int k = 0; k < 256; ++k) a2 += h[k] * w2[k * 256 + t];
    u2[t] = a2;
    __syncthreads();
    float fv = 0.f;
    if (t < 64) {
        float a3 = f1b[t];
        for (int k = 0; k < 256; ++k) a3 += u2[k] * f1w[k * 64 + t];
        fv = fmaxf(a3, 0.f) * f2w[t];
    }
    for (int off = 32; off; off >>= 1) fv += __shfl_down(fv, off, 64);
    if (t == 0) out[g] = fv + f2b[0];
}

// ---------- launch ----------
extern "C" void kernel_launch(void* const* d_in, const int* in_sizes, int n_in,
                              void* d_out, int out_size, void* d_ws, size_t ws_size,
                              hipStream_t stream) {
    const float* x         = (const float*)d_in[0];
    const float* edge_attr = (const float*)d_in[1];
    const float* e1_w1 = (const float*)d_in[2];
    const float* e1_b1 = (const float*)d_in[3];
    const float* e1_w2 = (const float*)d_in[4];
    const float* e1_b2 = (const float*)d_in[5];
    const float* g1_lw = (const float*)d_in[6];
    const float* g1_lb = (const float*)d_in[7];
    const float* g1_rw = (const float*)d_in[8];
    const float* g1_rb = (const float*)d_in[9];
    const float* g1_ew = (const float*)d_in[10];
    const float* g1_att = (const float*)d_in[11];
    const float* g1_bias = (const float*)d_in[12];
    const float* u1_w1 = (const float*)d_in[13];
    const float* u1_b1 = (const float*)d_in[14];
    const float* u1_w2 = (const float*)d_in[15];
    const float* u1_b2 = (const float*)d_in[16];
    const float* bn_n_g = (const float*)d_in[17];
    const float* bn_n_b = (const float*)d_in[18];
    const float* bn_e_g = (const float*)d_in[19];
    const float* bn_e_b = (const float*)d_in[20];
    const float* bn_u_g = (const float*)d_in[21];
    const float* bn_u_b = (const float*)d_in[22];
    const float* e2_w1 = (const float*)d_in[23];
    const float* e2_b1 = (const float*)d_in[24];
    const float* e2_w2 = (const float*)d_in[25];
    const float* e2_b2 = (const float*)d_in[26];
    const float* g2_lw = (const float*)d_in[27];
    const float* g2_lb = (const float*)d_in[28];
    const float* g2_rw = (const float*)d_in[29];
    const float* g2_rb = (const float*)d_in[30];
    const float* g2_ew = (const float*)d_in[31];
    const float* g2_att = (const float*)d_in[32];
    const float* g2_bias = (const float*)d_in[33];
    const float* u2_w1 = (const float*)d_in[34];
    const float* u2_b1 = (const float*)d_in[35];
    const float* u2_w2 = (const float*)d_in[36];
    const float* u2_b2 = (const float*)d_in[37];
    const float* fc1_w = (const float*)d_in[38];
    const float* fc1_b = (const float*)d_in[39];
    const float* fc2_w = (const float*)d_in[40];
    const float* fc2_b = (const float*)d_in[41];
    const int* edge_index = (const int*)d_in[42];
    const int* batch = (const int*)d_in[43];

    const int N = in_sizes[0] / 64;
    const int E = in_sizes[1] / 16;
    const int NT = E + N;
    const int G = G_GRAPHS;
    const int* src = edge_index;
    const int* dst = edge_index + E;
    const int NB = (NT + 31) / 32;
    const int NSB = (N + 2047) / 2048;   // scan blocks

    // workspace carve (x1bn aliases xr; pre2 lives in xl during edge_mlp2)
    char* p = (char*)d_ws;
    auto alloc = [&](size_t bytes) { char* r = p; p += (bytes + 255) & ~(size_t)255; return r; };
    bf16* xl    = (bf16*)alloc((size_t)N * 256 * 2);
    bf16* xr    = (bf16*)alloc((size_t)N * 256 * 2);
    bf16* x1bn  = xr;
    unsigned char* ee8 = (unsigned char*)alloc((size_t)NT * 256);
    bf16* pre1  = (bf16*)alloc((size_t)N * 128 * 2);
    int* degi   = (int*)alloc((size_t)N * 4);
    int* off    = (int*)alloc((size_t)(N + 1) * 4);
    int* fillc  = (int*)alloc((size_t)N * 4);
    int* csr_src = (int*)alloc((size_t)NT * 4);
    int* csr_dst = (int*)alloc((size_t)NT * 4);
    int* csr_eid = (int*)alloc((size_t)NT * 4);
    int* bsum   = (int*)alloc((size_t)(NSB + 1) * 4);
    int* boff   = (int*)alloc((size_t)(NSB + 1) * 4);
    float* pooled = (float*)alloc((size_t)G * 256 * 4);
    float* u1bn = (float*)alloc((size_t)G * 256 * 4);
    short* w1s  = (short*)alloc((size_t)20 * 8 * 64 * 8 * 2);
    short* w2s  = (short*)alloc((size_t)4 * 8 * 64 * 8 * 2);
    float* b1x  = (float*)alloc((size_t)256 * 4);
    short* w1p  = (short*)alloc((size_t)16 * 64 * 8 * 2);
    short* w1c  = (short*)alloc((size_t)4 * 64 * 8 * 2);
    short* w2s1 = (short*)alloc((size_t)16 * 64 * 8 * 2);
    short* ews1 = (short*)alloc((size_t)4 * 16 * 64 * 8 * 2);
    short* ews2 = (short*)alloc((size_t)4 * 16 * 64 * 8 * 2);
    short* nw1  = (short*)alloc((size_t)2 * 32 * 64 * 8 * 2);
    short* nw2  = (short*)alloc((size_t)8 * 32 * 64 * 8 * 2);
    short* nwp  = (short*)alloc((size_t)8 * 16 * 64 * 8 * 2);

    // ===== CSR build =====
    hipMemsetAsync(degi, 0, (size_t)N * 4, stream);
    hipMemsetAsync(fillc, 0, (size_t)N * 4, stream);
    hipMemsetAsync(pooled, 0, (size_t)G * 256 * 4, stream);
    degi_k<<<(E + 255) / 256, 256, 0, stream>>>(dst, degi, E);
    scan_blk_k<<<NSB, 1024, 0, stream>>>(degi, off, bsum, N);
    scan_top_k<<<1, 64, 0, stream>>>(bsum, boff, off, NSB, N);
    scan_add_k<<<(N + 255) / 256, 256, 0, stream>>>(off, boff, N);
    fill_csr_k<<<(max(E, N) + 255) / 256, 256, 0, stream>>>(src, dst, off, fillc,
                                                            csr_src, csr_dst, csr_eid, E, N);

    // ===== layer 1 =====
    conv_weights1_k<<<9, 256, 0, stream>>>(e1_w1, e1_w2, w1p, w1c, w2s1);
    conv_ew_k<<<16, 256, 0, stream>>>(g1_ew, ews1);
    conv_ew_k<<<16, 256, 0, stream>>>(g2_ew, ews2);
    conv_nodew_k<64><<<16, 256, 0, stream>>>(g1_lw, g1_rw, nw1);
    conv_nodew_k<256><<<64, 256, 0, stream>>>(g2_lw, g2_rw, nw2);
    conv_pre2w_k<<<32, 256, 0, stream>>>(e2_w1, nwp);
    pre1_mfma_k<<<(N + 15) / 16, 256, 0, stream>>>(x, w1p, e1_b1, pre1, N);
    edge_mlp1_mfma_k<<<NB, 256, 0, stream>>>(pre1, edge_attr, csr_src, csr_dst, csr_eid,
                                             w1c, w2s1, e1_b2, ews1, ee8, NT, E);
    node_linear_mfma_k<64, float><<<(N + 15) / 16, 256, 0, stream>>>(x, nw1, g1_lb, g1_rb, xl, xr, N);
    gat_fused_k<true><<<(N + 3) / 4, 256, 0, stream>>>(ee8, xl, xr, off, csr_src,
                                                       g1_att, g1_bias, bn_n_g, bn_n_b,
                                                       batch, x1bn, pooled, N);
    global_mlp1_k<<<G, 256, 0, stream>>>(pooled, u1_w1, u1_b1, u1_w2, u1_b2, bn_u_g, bn_u_b, u1bn);

    // ===== layer 2 =====
    conv_weights_k<<<50, 256, 0, stream>>>(e2_w1, e2_w2, e2_b1, bn_e_g, bn_e_b, w1s, w2s, b1x);
    pre_mfma_k<<<(N + 15) / 16, 256, 0, stream>>>(x1bn, nwp, b1x, xl, N);
    edge_mlp2_mfma_k<<<NB, 256, 0, stream>>>(xl, pre1, edge_attr, csr_src, csr_dst, csr_eid,
                                             w1c, w2s1, e1_b2, w1s, w2s, e2_b2, ews2,
                                             ee8, NT, E);
    node_linear_mfma_k<256, bf16><<<(N + 15) / 16, 256, 0, stream>>>(x1bn, nw2, g2_lb, g2_rb, xl, xr, N);
    hipMemsetAsync(pooled, 0, (size_t)G * 256 * 4, stream);
    gat_fused_k<false><<<(N + 3) / 4, 256, 0, stream>>>(ee8, xl, xr, off, csr_src,
                                                        g2_att, g2_bias, nullptr, nullptr,
                                                        batch, nullptr, pooled, N);
    final_mlp_k<<<G, 256, 0, stream>>>(u1bn, pooled, u2_w1, u2_b1, u2_w2, u2_b2,
                                       fc1_w, fc1_b, fc2_w, fc2_b, (float*)d_out);
}